// Round 1
// baseline (16001.024 us; speedup 1.0000x reference)
//
#include <hip/hip_runtime.h>

// Problem constants (from reference). n_layers / n_heads arrive as device
// scalars but are fixed by setup_inputs(); hard-coded for determinism.
constexpr int Bsz  = 4;
constexpr int Tlen = 1024;
constexpr int Cdim = 1024;
constexpr int NH   = 16;
constexpr int DHd  = 64;
constexpr int DFF  = 4096;
constexpr int VOC  = 65;
constexpr int NL   = 6;
constexpr int Mrow = Bsz * Tlen;   // 4096 token rows

// ---------------------------------------------------------------- embedding
__global__ __launch_bounds__(256) void embed_kernel(
    const int* __restrict__ tok, const float* __restrict__ Wtok,
    const float* __restrict__ Wpos, float* __restrict__ X) {
  int bt = blockIdx.x;                 // b*T + t
  int t  = bt & (Tlen - 1);
  int id = tok[bt];
  float4 a = reinterpret_cast<const float4*>(Wtok + (size_t)id * Cdim)[threadIdx.x];
  float4 p = reinterpret_cast<const float4*>(Wpos + (size_t)t  * Cdim)[threadIdx.x];
  float4 o{a.x + p.x, a.y + p.y, a.z + p.z, a.w + p.w};
  reinterpret_cast<float4*>(X + (size_t)bt * Cdim)[threadIdx.x] = o;
}

// ------------------------------------------------------------------- GEMM
// C[M,N] = A[M,K] @ W[K,N] + bias, optional ReLU.  M multiple of 64, K of 16.
// 64x64 tile, 256 threads, 4x4 microtile. LDS A stored transposed so both
// operand reads are contiguous float4 (16B-aligned via 68-float pitch).
template <bool RELU>
__global__ __launch_bounds__(256) void gemm_kernel(
    const float* __restrict__ Ain, const float* __restrict__ W,
    const float* __restrict__ bias, float* __restrict__ Cout, int N, int Kd) {
  __shared__ float As[16][68];   // [k][row]
  __shared__ float Ws[16][68];   // [k][col]
  const int tid = threadIdx.x;
  const int tx = tid & 15, ty = tid >> 4;
  const int row0 = blockIdx.x * 64, col0 = blockIdx.y * 64;
  float acc[4][4] = {};
  for (int k0 = 0; k0 < Kd; k0 += 16) {
    {  // A tile: 64 rows x 16 k, float4 along K, store transposed
      int r = tid >> 2;
      int c = (tid & 3) * 4;
      float4 av = *reinterpret_cast<const float4*>(
          &Ain[(size_t)(row0 + r) * Kd + k0 + c]);
      As[c + 0][r] = av.x; As[c + 1][r] = av.y;
      As[c + 2][r] = av.z; As[c + 3][r] = av.w;
    }
    {  // W tile: 16 k x 64 cols, coalesced along N, guard col<N
      int wr = tid >> 6;
      int wc = tid & 63;
      int col = col0 + wc;
#pragma unroll
      for (int i = 0; i < 4; ++i) {
        int rr = wr * 4 + i;
        Ws[rr][wc] = (col < N) ? W[(size_t)(k0 + rr) * N + col] : 0.f;
      }
    }
    __syncthreads();
#pragma unroll
    for (int kk = 0; kk < 16; ++kk) {
      float a[4], b[4];
      *reinterpret_cast<float4*>(a) =
          *reinterpret_cast<const float4*>(&As[kk][ty * 4]);
      *reinterpret_cast<float4*>(b) =
          *reinterpret_cast<const float4*>(&Ws[kk][tx * 4]);
#pragma unroll
      for (int i = 0; i < 4; ++i)
#pragma unroll
        for (int j = 0; j < 4; ++j) acc[i][j] = fmaf(a[i], b[j], acc[i][j]);
    }
    __syncthreads();
  }
#pragma unroll
  for (int i = 0; i < 4; ++i) {
    int row = row0 + ty * 4 + i;
#pragma unroll
    for (int j = 0; j < 4; ++j) {
      int col = col0 + tx * 4 + j;
      if (col < N) {
        float v = acc[i][j] + bias[col];
        if (RELU) v = fmaxf(v, 0.f);
        Cout[(size_t)row * N + col] = v;
      }
    }
  }
}

// --------------------------------------------------------------- attention
// One wave per query row; block = 4 waves over 4 consecutive queries of one
// (b,h). Scores kept in LDS; scale = 1/sqrt(C) = 1/32 (reference divides by
// sqrt of FULL d_k, not per-head).
__global__ __launch_bounds__(256) void attn_kernel(
    const float* __restrict__ Q, const float* __restrict__ Km,
    const float* __restrict__ Vm, float* __restrict__ Hout) {
  __shared__ float qs[4][64];
  __shared__ float sc[4][1024];
  const int w    = threadIdx.x >> 6;
  const int lane = threadIdx.x & 63;
  const int q    = blockIdx.x * 4 + w;
  const int bh   = blockIdx.y;
  const int b    = bh >> 4, h = bh & 15;
  const size_t base = ((size_t)b * Tlen) * Cdim + (size_t)h * 64;

  float qv = Q[base + (size_t)q * Cdim + lane] * (1.f / 32.f);
  qs[w][lane] = qv;
  __syncthreads();

  const int nk = q + 1;  // causal: keys 0..q
  float m = -1e30f;
  for (int kk = lane; kk < nk; kk += 64) {
    const float* kr = &Km[base + (size_t)kk * Cdim];
    float dot = 0.f;
#pragma unroll
    for (int d = 0; d < 64; d += 4) {
      float4 kv = *reinterpret_cast<const float4*>(&kr[d]);
      dot += qs[w][d] * kv.x + qs[w][d + 1] * kv.y +
             qs[w][d + 2] * kv.z + qs[w][d + 3] * kv.w;
    }
    sc[w][kk] = dot;
    m = fmaxf(m, dot);
  }
#pragma unroll
  for (int off = 32; off; off >>= 1) m = fmaxf(m, __shfl_xor(m, off));
  __syncthreads();

  float s = 0.f;
  for (int kk = lane; kk < nk; kk += 64) {  // lane-private elements
    float e = __expf(sc[w][kk] - m);
    sc[w][kk] = e;
    s += e;
  }
#pragma unroll
  for (int off = 32; off; off >>= 1) s += __shfl_xor(s, off);
  const float inv = 1.f / s;
  __syncthreads();

  // PV: lane = head dim; V rows coalesced, sc broadcast from LDS
  float o0 = 0, o1 = 0, o2 = 0, o3 = 0;
  int kk = 0;
  for (; kk + 4 <= nk; kk += 4) {
    o0 += sc[w][kk + 0] * Vm[base + (size_t)(kk + 0) * Cdim + lane];
    o1 += sc[w][kk + 1] * Vm[base + (size_t)(kk + 1) * Cdim + lane];
    o2 += sc[w][kk + 2] * Vm[base + (size_t)(kk + 2) * Cdim + lane];
    o3 += sc[w][kk + 3] * Vm[base + (size_t)(kk + 3) * Cdim + lane];
  }
  for (; kk < nk; ++kk) o0 += sc[w][kk] * Vm[base + (size_t)kk * Cdim + lane];
  Hout[base + (size_t)q * Cdim + lane] = (o0 + o1 + o2 + o3) * inv;
}

// -------------------------------------------------- y = x + layer_norm(x)
__global__ __launch_bounds__(256) void ln_res_kernel(
    const float* __restrict__ Xi, const float* __restrict__ w,
    float* __restrict__ Y) {
  int row = blockIdx.x;
  float4 v = reinterpret_cast<const float4*>(Xi + (size_t)row * Cdim)[threadIdx.x];
  float s  = v.x + v.y + v.z + v.w;
  float ss = v.x * v.x + v.y * v.y + v.z * v.z + v.w * v.w;
#pragma unroll
  for (int off = 32; off; off >>= 1) {
    s  += __shfl_xor(s, off);
    ss += __shfl_xor(ss, off);
  }
  __shared__ float sw[4], ssw[4];
  int wv = threadIdx.x >> 6, ln = threadIdx.x & 63;
  if (ln == 0) { sw[wv] = s; ssw[wv] = ss; }
  __syncthreads();
  s  = sw[0] + sw[1] + sw[2] + sw[3];
  ss = ssw[0] + ssw[1] + ssw[2] + ssw[3];
  float mean = s * (1.f / Cdim);
  float var  = ss * (1.f / Cdim) - mean * mean;
  float rstd = rsqrtf(var + 1e-5f);
  float4 wv4 = reinterpret_cast<const float4*>(w)[threadIdx.x];
  float4 o;
  o.x = v.x + (v.x - mean) * rstd * wv4.x;
  o.y = v.y + (v.y - mean) * rstd * wv4.y;
  o.z = v.z + (v.z - mean) * rstd * wv4.z;
  o.w = v.w + (v.w - mean) * rstd * wv4.w;
  reinterpret_cast<float4*>(Y + (size_t)row * Cdim)[threadIdx.x] = o;
}

// ------------------------------------------- probs = softmax over T axis
__global__ __launch_bounds__(256) void softmaxT_kernel(
    const float* __restrict__ logits, float* __restrict__ probs) {
  int b = blockIdx.x / VOC;
  int v = blockIdx.x - b * VOC;
  const float* src = logits + (size_t)b * Tlen * VOC + v;
  float vals[4];
  float m = -1e30f;
#pragma unroll
  for (int i = 0; i < 4; ++i) {
    int t = threadIdx.x + 256 * i;
    vals[i] = src[(size_t)t * VOC];
    m = fmaxf(m, vals[i]);
  }
#pragma unroll
  for (int off = 32; off; off >>= 1) m = fmaxf(m, __shfl_xor(m, off));
  __shared__ float sm[4], ssum[4];
  int wv = threadIdx.x >> 6, ln = threadIdx.x & 63;
  if (ln == 0) sm[wv] = m;
  __syncthreads();
  m = fmaxf(fmaxf(sm[0], sm[1]), fmaxf(sm[2], sm[3]));
  float s = 0.f;
#pragma unroll
  for (int i = 0; i < 4; ++i) { vals[i] = __expf(vals[i] - m); s += vals[i]; }
#pragma unroll
  for (int off = 32; off; off >>= 1) s += __shfl_xor(s, off);
  if (ln == 0) ssum[wv] = s;
  __syncthreads();
  s = ssum[0] + ssum[1] + ssum[2] + ssum[3];
  float inv = 1.f / s;
  float* dst = probs + (size_t)b * Tlen * VOC + v;
#pragma unroll
  for (int i = 0; i < 4; ++i) {
    int t = threadIdx.x + 256 * i;
    dst[(size_t)t * VOC] = vals[i] * inv;
  }
}

// ------------------------- per-row -log_softmax_V(probs)[target] partials
__global__ __launch_bounds__(256) void loss_rows_kernel(
    const float* __restrict__ probs, const int* __restrict__ tgt,
    float* __restrict__ partial) {
  int wv = threadIdx.x >> 6, lane = threadIdx.x & 63;
  int row = blockIdx.x * 4 + wv;
  const float* p = probs + (size_t)row * VOC;
  float x0 = p[lane];
  float x1 = (lane == 0) ? p[64] : -1e30f;   // VOC=65: one extra element
  float m = fmaxf(x0, x1);
#pragma unroll
  for (int off = 32; off; off >>= 1) m = fmaxf(m, __shfl_xor(m, off));
  float s = __expf(x0 - m) + ((lane == 0) ? __expf(x1 - m) : 0.f);
#pragma unroll
  for (int off = 32; off; off >>= 1) s += __shfl_xor(s, off);
  if (lane == 0) {
    int tg = tgt[row];
    partial[row] = (p[tg] - m) - logf(s);
  }
}

__global__ __launch_bounds__(256) void loss_final_kernel(
    const float* __restrict__ partial, float* __restrict__ out) {
  float s = 0.f;
  for (int i = threadIdx.x; i < Mrow; i += 256) s += partial[i];
#pragma unroll
  for (int off = 32; off; off >>= 1) s += __shfl_xor(s, off);
  __shared__ float sw[4];
  int wv = threadIdx.x >> 6, ln = threadIdx.x & 63;
  if (ln == 0) sw[wv] = s;
  __syncthreads();
  if (threadIdx.x == 0) out[0] = -(sw[0] + sw[1] + sw[2] + sw[3]) / (float)Mrow;
}

// ------------------------------------------------------------------ launch
extern "C" void kernel_launch(void* const* d_in, const int* in_sizes, int n_in,
                              void* d_out, int out_size, void* d_ws,
                              size_t ws_size, hipStream_t stream) {
  (void)in_sizes; (void)n_in; (void)out_size; (void)ws_size;
  const int*   tok    = (const int*)d_in[0];
  const int*   target = (const int*)d_in[1];
  const float* Wtok   = (const float*)d_in[3];
  const float* Wpos   = (const float*)d_in[4];
  const float* Wq = (const float*)d_in[5];  const float* bq = (const float*)d_in[6];
  const float* Wk = (const float*)d_in[7];  const float* bk = (const float*)d_in[8];
  const float* Wv = (const float*)d_in[9];  const float* bv = (const float*)d_in[10];
  const float* W1 = (const float*)d_in[11]; const float* b1 = (const float*)d_in[12];
  const float* W2 = (const float*)d_in[13]; const float* b2 = (const float*)d_in[14];
  const float* lnw = (const float*)d_in[15];
  const float* Wf = (const float*)d_in[16]; const float* bf = (const float*)d_in[17];
  float* out = (float*)d_out;

  // workspace layout (floats): X | A(=Q,K,V then FF1) | Hb | F2 | LOG | PART
  float* X    = (float*)d_ws;
  float* A    = X  + (size_t)Mrow * Cdim;          // 16M floats
  float* Hb   = A  + (size_t)Mrow * DFF;
  float* F2   = Hb + (size_t)Mrow * Cdim;
  float* LOG  = F2 + (size_t)Mrow * Cdim;
  float* PART = LOG + (size_t)Mrow * VOC;
  float* Qp = A;
  float* Kp = A + (size_t)Mrow * Cdim;
  float* Vp = A + 2 * (size_t)Mrow * Cdim;

  embed_kernel<<<Mrow, 256, 0, stream>>>(tok, Wtok, Wpos, X);

  for (int l = 0; l < NL; ++l) {
    dim3 gq(Mrow / 64, Cdim / 64);
    gemm_kernel<false><<<gq, 256, 0, stream>>>(X, Wq, bq, Qp, Cdim, Cdim);
    gemm_kernel<false><<<gq, 256, 0, stream>>>(X, Wk, bk, Kp, Cdim, Cdim);
    gemm_kernel<false><<<gq, 256, 0, stream>>>(X, Wv, bv, Vp, Cdim, Cdim);
    attn_kernel<<<dim3(Tlen / 4, Bsz * NH), 256, 0, stream>>>(Qp, Kp, Vp, Hb);
    ln_res_kernel<<<Mrow, 256, 0, stream>>>(Hb, lnw, F2);          // h + ln(h)
    gemm_kernel<true><<<dim3(Mrow / 64, DFF / 64), 256, 0, stream>>>(
        F2, W1, b1, A, DFF, Cdim);                                 // relu(hW1+b1)
    gemm_kernel<false><<<dim3(Mrow / 64, Cdim / 64), 256, 0, stream>>>(
        A, W2, b2, Hb, Cdim, DFF);                                 // ff2
    ln_res_kernel<<<Mrow, 256, 0, stream>>>(Hb, lnw, X);           // ff + ln(ff)
  }

  gemm_kernel<false><<<dim3(Mrow / 64, 2), 256, 0, stream>>>(
      X, Wf, bf, LOG, VOC, Cdim);                                  // logits
  softmaxT_kernel<<<Bsz * VOC, 256, 0, stream>>>(LOG, out + 1);    // probs
  loss_rows_kernel<<<Mrow / 4, 256, 0, stream>>>(out + 1, target, PART);
  loss_final_kernel<<<1, 256, 0, stream>>>(PART, out);
}

// Round 2
// 1569.177 us; speedup vs baseline: 10.1971x; 10.1971x over previous
//
#include <hip/hip_runtime.h>

typedef __attribute__((ext_vector_type(8))) short bh8;    // 8 bf16 = 4 VGPR
typedef __attribute__((ext_vector_type(4))) float f4v;    // MFMA acc

constexpr int VOC = 65;
constexpr int NL  = 6;
constexpr int Mrow = 4096;   // B*T

__device__ inline float b2f(unsigned short u) {
  union { unsigned int i; float f; } x; x.i = ((unsigned int)u) << 16; return x.f;
}
__device__ inline unsigned short f2b(float f) {
  union { float f; unsigned int i; } x; x.f = f;
  return (unsigned short)((x.i + 0x7FFFu + ((x.i >> 16) & 1u)) >> 16);
}
__device__ inline void gld16(const void* g, void* l) {
  __builtin_amdgcn_global_load_lds(
      (const __attribute__((address_space(1))) unsigned int*)g,
      (__attribute__((address_space(3))) unsigned int*)l, 16, 0, 0);
}
// swizzled LDS b128 read from a row-major [rows][64 bf16] tile (128 B rows)
__device__ inline bh8 lds_swz(const unsigned short* base, int row, int colbyte) {
  int off = row * 128 + (colbyte ^ ((row & 7) << 4));
  return *(const bh8*)((const char*)base + off);
}
__device__ inline f4v mfma16(bh8 a, bh8 b, f4v c) {
  return __builtin_amdgcn_mfma_f32_16x16x32_bf16(a, b, c, 0, 0, 0);
}

// ---------------------------------------------------------------- weight prep
// dst[n][k] = bf16(src[k][n]); zero-fill when n >= N (for Wf padding to 128)
__global__ __launch_bounds__(256) void wt_conv(const float* __restrict__ src,
    unsigned short* __restrict__ dst, int K, int N) {
  __shared__ float t[32][33];
  int k0 = blockIdx.x * 32, n0 = blockIdx.y * 32;
  int tid = threadIdx.x;
#pragma unroll
  for (int i = 0; i < 4; ++i) {
    int idx = tid + i * 256;
    int kr = idx >> 5, nc = idx & 31;
    t[kr][nc] = (n0 + nc < N) ? src[(size_t)(k0 + kr) * N + n0 + nc] : 0.f;
  }
  __syncthreads();
#pragma unroll
  for (int i = 0; i < 4; ++i) {
    int idx = tid + i * 256;
    int nr = idx >> 5, kc = idx & 31;
    dst[(size_t)(n0 + nr) * K + k0 + kc] = f2b(t[kc][nr]);
  }
}

__global__ __launch_bounds__(256) void bias_prep(
    const float* __restrict__ bq, const float* __restrict__ bk,
    const float* __restrict__ bv, const float* __restrict__ bf,
    float* __restrict__ bqkv, float* __restrict__ bfp) {
  int i = blockIdx.x * 256 + threadIdx.x;
  if (i < 1024) bqkv[i] = bq[i];
  else if (i < 2048) bqkv[i] = bk[i - 1024];
  else if (i < 3072) bqkv[i] = bv[i - 2048];
  else if (i < 3200) bfp[i - 3072] = (i - 3072 < VOC) ? bf[i - 3072] : 0.f;
}

// ---------------------------------------------------------------- embedding
__global__ __launch_bounds__(256) void embed_bf(const int* __restrict__ tok,
    const float* __restrict__ Wtok, const float* __restrict__ Wpos,
    unsigned short* __restrict__ Xb) {
  int bt = blockIdx.x, t = bt & 1023, tid = threadIdx.x;
  int id = tok[bt];
  float4 a = ((const float4*)(Wtok + (size_t)id * 1024))[tid];
  float4 p = ((const float4*)(Wpos + (size_t)t * 1024))[tid];
  ushort4 o;
  o.x = f2b(a.x + p.x); o.y = f2b(a.y + p.y);
  o.z = f2b(a.z + p.z); o.w = f2b(a.w + p.w);
  ((ushort4*)(Xb + (size_t)bt * 1024))[tid] = o;
}

// ------------------------------------------------------------------- GEMM
// C[M,N] = A[M,K] @ Bt[N,K]^T + bias. bf16 in, bf16 (or f32) out.
// 128x128 tile, BK=32, 4 waves (2x2), 4x4 fragments of 16x16x32 MFMA.
template <bool RELU, bool F32OUT>
__global__ __launch_bounds__(256) void gemm_mfma(
    const unsigned short* __restrict__ A, const unsigned short* __restrict__ Bt,
    const float* __restrict__ bias, void* __restrict__ Cout, int N, int K) {
  __shared__ unsigned short As[128 * 32];   // [m][k]
  __shared__ unsigned short Bs[128 * 32];   // [n][k]
  const int tid = threadIdx.x;
  const int lane = tid & 63, w = tid >> 6;
  const int wr = w >> 1, wc = w & 1;
  const int lr = lane & 15, lh = lane >> 4;
  const long row0 = (long)blockIdx.x * 128, col0 = (long)blockIdx.y * 128;
  f4v acc[4][4];
#pragma unroll
  for (int i = 0; i < 4; ++i)
#pragma unroll
    for (int j = 0; j < 4; ++j) acc[i][j] = f4v{0.f, 0.f, 0.f, 0.f};
  const int gr = tid >> 2, gk = (tid & 3) * 8;
  const unsigned short* Ap = A + (row0 + gr) * (long)K + gk;
  const unsigned short* Bp = Bt + (col0 + gr) * (long)K + gk;
  for (int k0 = 0; k0 < K; k0 += 32) {
    __syncthreads();
    gld16(Ap + k0, &As[tid * 8]);
    gld16(Ap + 64 * (long)K + k0, &As[2048 + tid * 8]);
    gld16(Bp + k0, &Bs[tid * 8]);
    gld16(Bp + 64 * (long)K + k0, &Bs[2048 + tid * 8]);
    __syncthreads();
    bh8 a[4], b[4];
#pragma unroll
    for (int mi = 0; mi < 4; ++mi)
      a[mi] = *(const bh8*)&As[(wr * 64 + mi * 16 + lr) * 32 + lh * 8];
#pragma unroll
    for (int ni = 0; ni < 4; ++ni)
      b[ni] = *(const bh8*)&Bs[(wc * 64 + ni * 16 + lr) * 32 + lh * 8];
#pragma unroll
    for (int mi = 0; mi < 4; ++mi)
#pragma unroll
      for (int ni = 0; ni < 4; ++ni)
        acc[mi][ni] = mfma16(a[mi], b[ni], acc[mi][ni]);
  }
#pragma unroll
  for (int mi = 0; mi < 4; ++mi) {
#pragma unroll
    for (int ni = 0; ni < 4; ++ni) {
      long col = col0 + wc * 64 + ni * 16 + lr;
      float bb = bias[col];
#pragma unroll
      for (int r = 0; r < 4; ++r) {
        long row = row0 + wr * 64 + mi * 16 + lh * 4 + r;
        float v = acc[mi][ni][r] + bb;
        if (RELU) v = fmaxf(v, 0.f);
        if (F32OUT) ((float*)Cout)[row * N + col] = v;
        else ((unsigned short*)Cout)[row * N + col] = f2b(v);
      }
    }
  }
}

// ------------------------------------------ V transpose: Vt[bh][dh][t] bf16
__global__ __launch_bounds__(256) void transpose_v(
    const unsigned short* __restrict__ QKV, unsigned short* __restrict__ Vt) {
  __shared__ unsigned short tile[64][80];   // pad to 160B rows (16B aligned)
  int tt = blockIdx.x, bh = blockIdx.y;
  int b = bh >> 4, h = bh & 15;
  int tid = threadIdx.x;
#pragma unroll
  for (int it = 0; it < 2; ++it) {
    int idx = tid + it * 256;           // 0..511
    int r = idx >> 3, c8 = (idx & 7) * 8;
    uint4 d = *(const uint4*)(QKV + (size_t)(b * 1024 + tt * 64 + r) * 3072 +
                              2048 + h * 64 + c8);
    *(uint4*)&tile[r][c8] = d;
  }
  __syncthreads();
#pragma unroll
  for (int it = 0; it < 2; ++it) {
    int idx = tid + it * 256;
    int d = idx >> 3, t8 = (idx & 7) * 8;
    unsigned short tmp[8];
#pragma unroll
    for (int j = 0; j < 8; ++j) tmp[j] = tile[t8 + j][d];
    *(uint4*)(Vt + (size_t)(bh * 64 + d) * 1024 + tt * 64 + t8) = *(uint4*)tmp;
  }
}

// ------------------------------------------------- flash attention (MFMA)
// grid (qtile=T/64, bh=64); 4 waves x 16 q-rows. scale = 1/sqrt(1024).
__global__ __launch_bounds__(256) void attn_mfma(
    const unsigned short* __restrict__ QKV, const unsigned short* __restrict__ Vt,
    unsigned short* __restrict__ Hout) {
  __shared__ unsigned short Ks[64 * 64];     // [key][dh]  swizzled
  __shared__ unsigned short Vs[64 * 64];     // [dh][key]  swizzled
  __shared__ unsigned short Ps[4][16 * 64];  // per-wave [q][key] swizzled
  const int tid = threadIdx.x, w = tid >> 6, lane = tid & 63;
  const int qt = blockIdx.x, bh = blockIdx.y;
  const int b = bh >> 4, h = bh & 15;
  const int lr = lane & 15, lh = lane >> 4;

  // Q fragments, register-resident for the whole KV loop
  const unsigned short* qp =
      QKV + (size_t)(b * 1024 + qt * 64 + w * 16 + lr) * 3072 + h * 64 + lh * 8;
  bh8 aq0 = *(const bh8*)qp;
  bh8 aq1 = *(const bh8*)(qp + 32);

  f4v o[4];
  float mrow[4], lrw[4];
#pragma unroll
  for (int i = 0; i < 4; ++i) {
    o[i] = f4v{0.f, 0.f, 0.f, 0.f};
    mrow[i] = -1e30f; lrw[i] = 0.f;
  }
  const int r8 = tid >> 3, slot = tid & 7;
  unsigned short* pw = &Ps[w][0];

  for (int kt = 0; kt <= qt; ++kt) {
    __syncthreads();
    {  // stage K tile [64key][64dh] and V^T tile [64dh][64key], pre-swizzled src
      int r = r8, c8 = (slot ^ (r & 7)) * 8;
      gld16(QKV + (size_t)(b * 1024 + kt * 64 + r) * 3072 + 1024 + h * 64 + c8,
            &Ks[tid * 8]);
      gld16(Vt + (size_t)(bh * 64 + r) * 1024 + kt * 64 + c8, &Vs[tid * 8]);
      r = r8 + 32; c8 = (slot ^ (r & 7)) * 8;
      gld16(QKV + (size_t)(b * 1024 + kt * 64 + r) * 3072 + 1024 + h * 64 + c8,
            &Ks[2048 + tid * 8]);
      gld16(Vt + (size_t)(bh * 64 + r) * 1024 + kt * 64 + c8, &Vs[2048 + tid * 8]);
    }
    __syncthreads();

    // S = (Q K^T) * 1/32, causal mask
    f4v s[4];
#pragma unroll
    for (int nt = 0; nt < 4; ++nt) {
      bh8 k0 = lds_swz(Ks, nt * 16 + lr, lh * 16);
      bh8 k1 = lds_swz(Ks, nt * 16 + lr, lh * 16 + 64);
      f4v z = f4v{0.f, 0.f, 0.f, 0.f};
      z = mfma16(aq0, k0, z);
      z = mfma16(aq1, k1, z);
      s[nt] = z;
    }
    const bool diag = (kt == qt);
#pragma unroll
    for (int nt = 0; nt < 4; ++nt) {
      int kloc = nt * 16 + lr;          // key index within tile
#pragma unroll
      for (int r = 0; r < 4; ++r) {
        float v = s[nt][r] * 0.03125f;
        if (diag && kloc > w * 16 + lh * 4 + r) v = -1e30f;
        s[nt][r] = v;
      }
    }
    // online softmax row stats (row = q, spread over 16 lanes = cols)
    float corr[4];
#pragma unroll
    for (int r = 0; r < 4; ++r) {
      float tm = fmaxf(fmaxf(s[0][r], s[1][r]), fmaxf(s[2][r], s[3][r]));
      tm = fmaxf(tm, __shfl_xor(tm, 1));
      tm = fmaxf(tm, __shfl_xor(tm, 2));
      tm = fmaxf(tm, __shfl_xor(tm, 4));
      tm = fmaxf(tm, __shfl_xor(tm, 8));
      float mn = fmaxf(mrow[r], tm);
      corr[r] = __expf(mrow[r] - mn);
      mrow[r] = mn;
      float sum = 0.f;
#pragma unroll
      for (int nt = 0; nt < 4; ++nt) {
        float e = __expf(s[nt][r] - mn);
        s[nt][r] = e;
        sum += e;
      }
      sum += __shfl_xor(sum, 1);
      sum += __shfl_xor(sum, 2);
      sum += __shfl_xor(sum, 4);
      sum += __shfl_xor(sum, 8);
      lrw[r] = lrw[r] * corr[r] + sum;
    }
    // P -> per-wave LDS (bf16, swizzled); D-layout -> A-layout transpose
#pragma unroll
    for (int nt = 0; nt < 4; ++nt)
#pragma unroll
      for (int r = 0; r < 4; ++r) {
        int prow = lh * 4 + r;
        int cb = (nt * 16 + lr) * 2;
        *(unsigned short*)((char*)pw + prow * 128 + (cb ^ ((prow & 7) << 4))) =
            f2b(s[nt][r]);
      }
    // rescale O, then O += P @ V
#pragma unroll
    for (int nt = 0; nt < 4; ++nt)
#pragma unroll
      for (int r = 0; r < 4; ++r) o[nt][r] *= corr[r];
    bh8 pa0 = lds_swz(pw, lr, lh * 16);
    bh8 pa1 = lds_swz(pw, lr, lh * 16 + 64);
#pragma unroll
    for (int nt = 0; nt < 4; ++nt) {
      bh8 v0 = lds_swz(Vs, nt * 16 + lr, lh * 16);
      bh8 v1 = lds_swz(Vs, nt * 16 + lr, lh * 16 + 64);
      o[nt] = mfma16(pa0, v0, o[nt]);
      o[nt] = mfma16(pa1, v1, o[nt]);
    }
  }
  // epilogue: normalize and store bf16
#pragma unroll
  for (int r = 0; r < 4; ++r) lrw[r] = 1.f / lrw[r];
  const size_t rowb = (size_t)(b * 1024 + qt * 64 + w * 16);
#pragma unroll
  for (int nt = 0; nt < 4; ++nt) {
    int col = h * 64 + nt * 16 + lr;
#pragma unroll
    for (int r = 0; r < 4; ++r)
      Hout[(rowb + lh * 4 + r) * 1024 + col] = f2b(o[nt][r] * lrw[r]);
  }
}

// -------------------------------------------------- y = x + layer_norm(x)
__global__ __launch_bounds__(256) void ln_res_bf(
    const unsigned short* __restrict__ Xi, const float* __restrict__ wln,
    unsigned short* __restrict__ Y) {
  int row = blockIdx.x, tid = threadIdx.x;
  ushort4 u = ((const ushort4*)(Xi + (size_t)row * 1024))[tid];
  float x0 = b2f(u.x), x1 = b2f(u.y), x2 = b2f(u.z), x3 = b2f(u.w);
  float s = x0 + x1 + x2 + x3;
  float ss = x0 * x0 + x1 * x1 + x2 * x2 + x3 * x3;
#pragma unroll
  for (int off = 32; off; off >>= 1) {
    s += __shfl_xor(s, off);
    ss += __shfl_xor(ss, off);
  }
  __shared__ float sw[4], ssw[4];
  int wv = tid >> 6, ln = tid & 63;
  if (ln == 0) { sw[wv] = s; ssw[wv] = ss; }
  __syncthreads();
  s = sw[0] + sw[1] + sw[2] + sw[3];
  ss = ssw[0] + ssw[1] + ssw[2] + ssw[3];
  float mean = s * (1.f / 1024.f);
  float var = ss * (1.f / 1024.f) - mean * mean;
  float rstd = rsqrtf(var + 1e-5f);
  float4 wv4 = ((const float4*)wln)[tid];
  ushort4 out;
  out.x = f2b(x0 + (x0 - mean) * rstd * wv4.x);
  out.y = f2b(x1 + (x1 - mean) * rstd * wv4.y);
  out.z = f2b(x2 + (x2 - mean) * rstd * wv4.z);
  out.w = f2b(x3 + (x3 - mean) * rstd * wv4.w);
  ((ushort4*)(Y + (size_t)row * 1024))[tid] = out;
}

// ------------------------------------------- probs = softmax over T axis
__global__ __launch_bounds__(256) void softmaxT_kernel(
    const float* __restrict__ logits, float* __restrict__ probs) {
  int b = blockIdx.x / VOC;
  int v = blockIdx.x - b * VOC;
  const float* src = logits + (size_t)b * 1024 * 128 + v;
  float vals[4];
  float m = -1e30f;
#pragma unroll
  for (int i = 0; i < 4; ++i) {
    int t = threadIdx.x + 256 * i;
    vals[i] = src[(size_t)t * 128];
    m = fmaxf(m, vals[i]);
  }
#pragma unroll
  for (int off = 32; off; off >>= 1) m = fmaxf(m, __shfl_xor(m, off));
  __shared__ float sm[4], ssum[4];
  int wv = threadIdx.x >> 6, ln = threadIdx.x & 63;
  if (ln == 0) sm[wv] = m;
  __syncthreads();
  m = fmaxf(fmaxf(sm[0], sm[1]), fmaxf(sm[2], sm[3]));
  float s = 0.f;
#pragma unroll
  for (int i = 0; i < 4; ++i) { vals[i] = __expf(vals[i] - m); s += vals[i]; }
#pragma unroll
  for (int off = 32; off; off >>= 1) s += __shfl_xor(s, off);
  if (ln == 0) ssum[wv] = s;
  __syncthreads();
  s = ssum[0] + ssum[1] + ssum[2] + ssum[3];
  float inv = 1.f / s;
  float* dst = probs + (size_t)b * 1024 * VOC + v;
#pragma unroll
  for (int i = 0; i < 4; ++i) {
    int t = threadIdx.x + 256 * i;
    dst[(size_t)t * VOC] = vals[i] * inv;
  }
}

// ------------------------- per-row -log_softmax_V(probs)[target] partials
__global__ __launch_bounds__(256) void loss_rows_kernel(
    const float* __restrict__ probs, const int* __restrict__ tgt,
    float* __restrict__ partial) {
  int wv = threadIdx.x >> 6, lane = threadIdx.x & 63;
  int row = blockIdx.x * 4 + wv;
  const float* p = probs + (size_t)row * VOC;
  float x0 = p[lane];
  float x1 = (lane == 0) ? p[64] : -1e30f;
  float m = fmaxf(x0, x1);
#pragma unroll
  for (int off = 32; off; off >>= 1) m = fmaxf(m, __shfl_xor(m, off));
  float s = __expf(x0 - m) + ((lane == 0) ? __expf(x1 - m) : 0.f);
#pragma unroll
  for (int off = 32; off; off >>= 1) s += __shfl_xor(s, off);
  if (lane == 0) {
    int tg = tgt[row];
    partial[row] = (p[tg] - m) - logf(s);
  }
}

__global__ __launch_bounds__(256) void loss_final_kernel(
    const float* __restrict__ partial, float* __restrict__ out) {
  float s = 0.f;
  for (int i = threadIdx.x; i < Mrow; i += 256) s += partial[i];
#pragma unroll
  for (int off = 32; off; off >>= 1) s += __shfl_xor(s, off);
  __shared__ float sw[4];
  int wv = threadIdx.x >> 6, ln = threadIdx.x & 63;
  if (ln == 0) sw[wv] = s;
  __syncthreads();
  if (threadIdx.x == 0) out[0] = -(sw[0] + sw[1] + sw[2] + sw[3]) / (float)Mrow;
}

// ------------------------------------------------------------------ launch
extern "C" void kernel_launch(void* const* d_in, const int* in_sizes, int n_in,
                              void* d_out, int out_size, void* d_ws,
                              size_t ws_size, hipStream_t stream) {
  (void)in_sizes; (void)n_in; (void)out_size; (void)ws_size;
  const int*   tok    = (const int*)d_in[0];
  const int*   target = (const int*)d_in[1];
  const float* Wtok   = (const float*)d_in[3];
  const float* Wpos   = (const float*)d_in[4];
  const float* Wq = (const float*)d_in[5];  const float* bq = (const float*)d_in[6];
  const float* Wk = (const float*)d_in[7];  const float* bk = (const float*)d_in[8];
  const float* Wv = (const float*)d_in[9];  const float* bv = (const float*)d_in[10];
  const float* W1 = (const float*)d_in[11]; const float* b1 = (const float*)d_in[12];
  const float* W2 = (const float*)d_in[13]; const float* b2 = (const float*)d_in[14];
  const float* lnw = (const float*)d_in[15];
  const float* Wf = (const float*)d_in[16]; const float* bf = (const float*)d_in[17];
  float* out = (float*)d_out;

  char* p = (char*)d_ws;
  unsigned short* Xb    = (unsigned short*)p; p += (size_t)Mrow * 1024 * 2;
  unsigned short* QKVb  = (unsigned short*)p; p += (size_t)Mrow * 3072 * 2;
  unsigned short* Vt    = (unsigned short*)p; p += (size_t)64 * 64 * 1024 * 2;
  unsigned short* Hb    = (unsigned short*)p; p += (size_t)Mrow * 1024 * 2;
  unsigned short* F2b   = (unsigned short*)p; p += (size_t)Mrow * 1024 * 2;
  unsigned short* FF1b  = (unsigned short*)p; p += (size_t)Mrow * 4096 * 2;
  unsigned short* WqkvT = (unsigned short*)p; p += (size_t)3072 * 1024 * 2;
  unsigned short* W1T   = (unsigned short*)p; p += (size_t)4096 * 1024 * 2;
  unsigned short* W2T   = (unsigned short*)p; p += (size_t)1024 * 4096 * 2;
  unsigned short* WfT   = (unsigned short*)p; p += (size_t)128 * 1024 * 2;
  float* bqkv = (float*)p; p += 3072 * 4;
  float* bfp  = (float*)p; p += 128 * 4;
  float* LOG  = (float*)p; p += (size_t)Mrow * 128 * 4;
  float* PART = (float*)p; p += Mrow * 4;

  // weight prep (bf16, transposed to [N][K])
  wt_conv<<<dim3(32, 32), 256, 0, stream>>>(Wq, WqkvT,                1024, 1024);
  wt_conv<<<dim3(32, 32), 256, 0, stream>>>(Wk, WqkvT + 1024 * 1024,  1024, 1024);
  wt_conv<<<dim3(32, 32), 256, 0, stream>>>(Wv, WqkvT + 2048 * 1024,  1024, 1024);
  wt_conv<<<dim3(32, 128), 256, 0, stream>>>(W1, W1T, 1024, 4096);
  wt_conv<<<dim3(128, 32), 256, 0, stream>>>(W2, W2T, 4096, 1024);
  wt_conv<<<dim3(32, 4), 256, 0, stream>>>(Wf, WfT, 1024, VOC);
  bias_prep<<<13, 256, 0, stream>>>(bq, bk, bv, bf, bqkv, bfp);

  embed_bf<<<Mrow, 256, 0, stream>>>(tok, Wtok, Wpos, Xb);

  for (int l = 0; l < NL; ++l) {
    gemm_mfma<false, false><<<dim3(32, 24), 256, 0, stream>>>(
        Xb, WqkvT, bqkv, QKVb, 3072, 1024);
    transpose_v<<<dim3(16, 64), 256, 0, stream>>>(QKVb, Vt);
    attn_mfma<<<dim3(16, 64), 256, 0, stream>>>(QKVb, Vt, Hb);
    ln_res_bf<<<Mrow, 256, 0, stream>>>(Hb, lnw, F2b);            // h + ln(h)
    gemm_mfma<true, false><<<dim3(32, 32), 256, 0, stream>>>(
        F2b, W1T, b1, FF1b, 4096, 1024);                          // relu(hW1+b1)
    gemm_mfma<false, false><<<dim3(32, 8), 256, 0, stream>>>(
        FF1b, W2T, b2, Hb, 1024, 4096);                           // ff2
    ln_res_bf<<<Mrow, 256, 0, stream>>>(Hb, lnw, Xb);             // ff + ln(ff)
  }

  gemm_mfma<false, true><<<dim3(32, 1), 256, 0, stream>>>(
      Xb, WfT, bfp, LOG, 128, 1024);                              // logits (f32)
  softmaxT_kernel<<<4 * VOC, 256, 0, stream>>>(LOG, out + 1);
  loss_rows_kernel<<<Mrow / 4, 256, 0, stream>>>(out + 1, target, PART);
  loss_final_kernel<<<1, 256, 0, stream>>>(PART, out);
}

// Round 3
// 1341.035 us; speedup vs baseline: 11.9318x; 1.1701x over previous
//
#include <hip/hip_runtime.h>

typedef __attribute__((ext_vector_type(8))) short bh8;    // 8 bf16 = 4 VGPR
typedef __attribute__((ext_vector_type(4))) float f4v;    // MFMA acc

constexpr int VOC = 65;
constexpr int NL  = 6;
constexpr int Mrow = 4096;   // B*T

__device__ inline float b2f(unsigned short u) {
  union { unsigned int i; float f; } x; x.i = ((unsigned int)u) << 16; return x.f;
}
__device__ inline unsigned short f2b(float f) {
  union { float f; unsigned int i; } x; x.f = f;
  return (unsigned short)((x.i + 0x7FFFu + ((x.i >> 16) & 1u)) >> 16);
}
__device__ inline void gld16(const void* g, void* l) {
  __builtin_amdgcn_global_load_lds(
      (const __attribute__((address_space(1))) unsigned int*)g,
      (__attribute__((address_space(3))) unsigned int*)l, 16, 0, 0);
}
// swizzled LDS b128 read from a row-major [rows][64 bf16] tile (128 B rows)
__device__ inline bh8 lds_swz(const unsigned short* base, int row, int colbyte) {
  int off = row * 128 + (colbyte ^ ((row & 7) << 4));
  return *(const bh8*)((const char*)base + off);
}
__device__ inline f4v mfma16(bh8 a, bh8 b, f4v c) {
  return __builtin_amdgcn_mfma_f32_16x16x32_bf16(a, b, c, 0, 0, 0);
}

// ---------------------------------------------------------------- weight prep
// dst[n][k] = bf16(src[k][n]); zero-fill when n >= N (for Wf padding to 128)
__global__ __launch_bounds__(256) void wt_conv(const float* __restrict__ src,
    unsigned short* __restrict__ dst, int K, int N) {
  __shared__ float t[32][33];
  int k0 = blockIdx.x * 32, n0 = blockIdx.y * 32;
  int tid = threadIdx.x;
#pragma unroll
  for (int i = 0; i < 4; ++i) {
    int idx = tid + i * 256;
    int kr = idx >> 5, nc = idx & 31;
    t[kr][nc] = (n0 + nc < N) ? src[(size_t)(k0 + kr) * N + n0 + nc] : 0.f;
  }
  __syncthreads();
#pragma unroll
  for (int i = 0; i < 4; ++i) {
    int idx = tid + i * 256;
    int nr = idx >> 5, kc = idx & 31;
    dst[(size_t)(n0 + nr) * K + k0 + kc] = f2b(t[kc][nr]);
  }
}

__global__ __launch_bounds__(256) void bias_prep(
    const float* __restrict__ bq, const float* __restrict__ bk,
    const float* __restrict__ bv, const float* __restrict__ bf,
    float* __restrict__ bqkv, float* __restrict__ bfp) {
  int i = blockIdx.x * 256 + threadIdx.x;
  if (i < 1024) bqkv[i] = bq[i];
  else if (i < 2048) bqkv[i] = bk[i - 1024];
  else if (i < 3072) bqkv[i] = bv[i - 2048];
  else if (i < 3200) bfp[i - 3072] = (i - 3072 < VOC) ? bf[i - 3072] : 0.f;
}

// ---------------------------------------------------------------- embedding
__global__ __launch_bounds__(256) void embed_bf(const int* __restrict__ tok,
    const float* __restrict__ Wtok, const float* __restrict__ Wpos,
    unsigned short* __restrict__ Xb) {
  int bt = blockIdx.x, t = bt & 1023, tid = threadIdx.x;
  int id = tok[bt];
  float4 a = ((const float4*)(Wtok + (size_t)id * 1024))[tid];
  float4 p = ((const float4*)(Wpos + (size_t)t * 1024))[tid];
  ushort4 o;
  o.x = f2b(a.x + p.x); o.y = f2b(a.y + p.y);
  o.z = f2b(a.z + p.z); o.w = f2b(a.w + p.w);
  ((ushort4*)(Xb + (size_t)bt * 1024))[tid] = o;
}

// ------------------------------------------------------------------- GEMM
// C[M,N] = A[M,K] @ Bt[N,K]^T + bias. bf16 in, bf16 (or f32) out.
// TMxTN tile, BK=64, 4 waves (2x2). Both-sides XOR swizzle: LDS dest linear
// (global_load_lds requirement), global SOURCE k-chunk is inverse-permuted,
// ds_read applies the same involution -> MFMA sees identical data, banks
// spread 8-way (2 lanes/slot = free per m136).
template <int TM, int TN, bool RELU, bool F32OUT>
__global__ __launch_bounds__(256) void gemm_mfma(
    const unsigned short* __restrict__ A, const unsigned short* __restrict__ Bt,
    const float* __restrict__ bias, void* __restrict__ Cout, long N, long K) {
  constexpr int MI = TM / 32, NI = TN / 32;   // fragments per wave
  __shared__ unsigned short As[TM * 64];      // [m][64k] swizzled slots
  __shared__ unsigned short Bs[TN * 64];      // [n][64k]
  const int tid = threadIdx.x;
  const int lane = tid & 63, w = tid >> 6;
  const int wr = w >> 1, wc = w & 1;
  const int lr = lane & 15, lh = lane >> 4;
  const long row0 = (long)blockIdx.x * TM, col0 = (long)blockIdx.y * TN;

  f4v acc[MI][NI];
#pragma unroll
  for (int i = 0; i < MI; ++i)
#pragma unroll
    for (int j = 0; j < NI; ++j) acc[i][j] = f4v{0.f, 0.f, 0.f, 0.f};

  // staging: thread covers row rg (per 32-row group), k-chunk c = s^(rg&7)
  const int rg = tid >> 3, s = tid & 7;
  const int ch = s ^ (rg & 7);
  const unsigned short* Ap = A + (row0 + rg) * K + ch * 8;
  const unsigned short* Bp = Bt + (col0 + rg) * K + ch * 8;

  for (long k0 = 0; k0 < K; k0 += 64) {
    __syncthreads();
#pragma unroll
    for (int i = 0; i < MI; ++i)
      gld16(Ap + i * 32 * K + k0, &As[(i * 256 + tid) * 8]);
#pragma unroll
    for (int i = 0; i < NI; ++i)
      gld16(Bp + i * 32 * K + k0, &Bs[(i * 256 + tid) * 8]);
    __syncthreads();
#pragma unroll
    for (int ks = 0; ks < 2; ++ks) {
      bh8 a[MI], b[NI];
#pragma unroll
      for (int mi = 0; mi < MI; ++mi) {
        int m = wr * (TM / 2) + mi * 16 + lr;
        int slot = ((ks << 2) | lh) ^ (lr & 7);
        a[mi] = *(const bh8*)((const char*)As + m * 128 + slot * 16);
      }
#pragma unroll
      for (int ni = 0; ni < NI; ++ni) {
        int n = wc * (TN / 2) + ni * 16 + lr;
        int slot = ((ks << 2) | lh) ^ (lr & 7);
        b[ni] = *(const bh8*)((const char*)Bs + n * 128 + slot * 16);
      }
#pragma unroll
      for (int mi = 0; mi < MI; ++mi)
#pragma unroll
        for (int ni = 0; ni < NI; ++ni)
          acc[mi][ni] = mfma16(a[mi], b[ni], acc[mi][ni]);
    }
  }
#pragma unroll
  for (int mi = 0; mi < MI; ++mi) {
#pragma unroll
    for (int ni = 0; ni < NI; ++ni) {
      long col = col0 + wc * (TN / 2) + ni * 16 + lr;
      float bb = bias[col];
#pragma unroll
      for (int r = 0; r < 4; ++r) {
        long row = row0 + wr * (TM / 2) + mi * 16 + lh * 4 + r;
        float v = acc[mi][ni][r] + bb;
        if (RELU) v = fmaxf(v, 0.f);
        if (F32OUT) ((float*)Cout)[row * N + col] = v;
        else ((unsigned short*)Cout)[row * N + col] = f2b(v);
      }
    }
  }
}

// ------------------------------------------ V transpose: Vt[bh][dh][t] bf16
__global__ __launch_bounds__(256) void transpose_v(
    const unsigned short* __restrict__ QKV, unsigned short* __restrict__ Vt) {
  __shared__ unsigned short tile[64][80];   // pad to 160B rows (16B aligned)
  int tt = blockIdx.x, bh = blockIdx.y;
  int b = bh >> 4, h = bh & 15;
  int tid = threadIdx.x;
#pragma unroll
  for (int it = 0; it < 2; ++it) {
    int idx = tid + it * 256;           // 0..511
    int r = idx >> 3, c8 = (idx & 7) * 8;
    uint4 d = *(const uint4*)(QKV + (size_t)(b * 1024 + tt * 64 + r) * 3072 +
                              2048 + h * 64 + c8);
    *(uint4*)&tile[r][c8] = d;
  }
  __syncthreads();
#pragma unroll
  for (int it = 0; it < 2; ++it) {
    int idx = tid + it * 256;
    int d = idx >> 3, t8 = (idx & 7) * 8;
    unsigned short tmp[8];
#pragma unroll
    for (int j = 0; j < 8; ++j) tmp[j] = tile[t8 + j][d];
    *(uint4*)(Vt + (size_t)(bh * 64 + d) * 1024 + tt * 64 + t8) = *(uint4*)tmp;
  }
}

// ------------------------------------------------- flash attention (MFMA)
// grid (qtile=T/64, bh=64); 4 waves x 16 q-rows. scale = 1/sqrt(1024).
__global__ __launch_bounds__(256) void attn_mfma(
    const unsigned short* __restrict__ QKV, const unsigned short* __restrict__ Vt,
    unsigned short* __restrict__ Hout) {
  __shared__ unsigned short Ks[64 * 64];     // [key][dh]  swizzled
  __shared__ unsigned short Vs[64 * 64];     // [dh][key]  swizzled
  __shared__ unsigned short Ps[4][16 * 64];  // per-wave [q][key] swizzled
  const int tid = threadIdx.x, w = tid >> 6, lane = tid & 63;
  const int qt = blockIdx.x, bh = blockIdx.y;
  const int b = bh >> 4, h = bh & 15;
  const int lr = lane & 15, lh = lane >> 4;

  // Q fragments, register-resident for the whole KV loop
  const unsigned short* qp =
      QKV + (size_t)(b * 1024 + qt * 64 + w * 16 + lr) * 3072 + h * 64 + lh * 8;
  bh8 aq0 = *(const bh8*)qp;
  bh8 aq1 = *(const bh8*)(qp + 32);

  f4v o[4];
  float mrow[4], lrw[4];
#pragma unroll
  for (int i = 0; i < 4; ++i) {
    o[i] = f4v{0.f, 0.f, 0.f, 0.f};
    mrow[i] = -1e30f; lrw[i] = 0.f;
  }
  const int r8 = tid >> 3, slot = tid & 7;
  unsigned short* pw = &Ps[w][0];

  for (int kt = 0; kt <= qt; ++kt) {
    __syncthreads();
    {  // stage K tile [64key][64dh] and V^T tile [64dh][64key], pre-swizzled src
      int r = r8, c8 = (slot ^ (r & 7)) * 8;
      gld16(QKV + (size_t)(b * 1024 + kt * 64 + r) * 3072 + 1024 + h * 64 + c8,
            &Ks[tid * 8]);
      gld16(Vt + (size_t)(bh * 64 + r) * 1024 + kt * 64 + c8, &Vs[tid * 8]);
      r = r8 + 32; c8 = (slot ^ (r & 7)) * 8;
      gld16(QKV + (size_t)(b * 1024 + kt * 64 + r) * 3072 + 1024 + h * 64 + c8,
            &Ks[2048 + tid * 8]);
      gld16(Vt + (size_t)(bh * 64 + r) * 1024 + kt * 64 + c8, &Vs[2048 + tid * 8]);
    }
    __syncthreads();

    // S = (Q K^T) * 1/32, causal mask
    f4v s[4];
#pragma unroll
    for (int nt = 0; nt < 4; ++nt) {
      bh8 k0 = lds_swz(Ks, nt * 16 + lr, lh * 16);
      bh8 k1 = lds_swz(Ks, nt * 16 + lr, lh * 16 + 64);
      f4v z = f4v{0.f, 0.f, 0.f, 0.f};
      z = mfma16(aq0, k0, z);
      z = mfma16(aq1, k1, z);
      s[nt] = z;
    }
    const bool diag = (kt == qt);
#pragma unroll
    for (int nt = 0; nt < 4; ++nt) {
      int kloc = nt * 16 + lr;          // key index within tile
#pragma unroll
      for (int r = 0; r < 4; ++r) {
        float v = s[nt][r] * 0.03125f;
        if (diag && kloc > w * 16 + lh * 4 + r) v = -1e30f;
        s[nt][r] = v;
      }
    }
    // online softmax row stats (row = q, spread over 16 lanes = cols)
    float corr[4];
#pragma unroll
    for (int r = 0; r < 4; ++r) {
      float tm = fmaxf(fmaxf(s[0][r], s[1][r]), fmaxf(s[2][r], s[3][r]));
      tm = fmaxf(tm, __shfl_xor(tm, 1));
      tm = fmaxf(tm, __shfl_xor(tm, 2));
      tm = fmaxf(tm, __shfl_xor(tm, 4));
      tm = fmaxf(tm, __shfl_xor(tm, 8));
      float mn = fmaxf(mrow[r], tm);
      corr[r] = __expf(mrow[r] - mn);
      mrow[r] = mn;
      float sum = 0.f;
#pragma unroll
      for (int nt = 0; nt < 4; ++nt) {
        float e = __expf(s[nt][r] - mn);
        s[nt][r] = e;
        sum += e;
      }
      sum += __shfl_xor(sum, 1);
      sum += __shfl_xor(sum, 2);
      sum += __shfl_xor(sum, 4);
      sum += __shfl_xor(sum, 8);
      lrw[r] = lrw[r] * corr[r] + sum;
    }
    // P -> per-wave LDS (bf16, swizzled); D-layout -> A-layout transpose
#pragma unroll
    for (int nt = 0; nt < 4; ++nt)
#pragma unroll
      for (int r = 0; r < 4; ++r) {
        int prow = lh * 4 + r;
        int cb = (nt * 16 + lr) * 2;
        *(unsigned short*)((char*)pw + prow * 128 + (cb ^ ((prow & 7) << 4))) =
            f2b(s[nt][r]);
      }
    // rescale O, then O += P @ V
#pragma unroll
    for (int nt = 0; nt < 4; ++nt)
#pragma unroll
      for (int r = 0; r < 4; ++r) o[nt][r] *= corr[r];
    bh8 pa0 = lds_swz(pw, lr, lh * 16);
    bh8 pa1 = lds_swz(pw, lr, lh * 16 + 64);
#pragma unroll
    for (int nt = 0; nt < 4; ++nt) {
      bh8 v0 = lds_swz(Vs, nt * 16 + lr, lh * 16);
      bh8 v1 = lds_swz(Vs, nt * 16 + lr, lh * 16 + 64);
      o[nt] = mfma16(pa0, v0, o[nt]);
      o[nt] = mfma16(pa1, v1, o[nt]);
    }
  }
  // epilogue: normalize and store bf16
#pragma unroll
  for (int r = 0; r < 4; ++r) lrw[r] = 1.f / lrw[r];
  const size_t rowb = (size_t)(b * 1024 + qt * 64 + w * 16);
#pragma unroll
  for (int nt = 0; nt < 4; ++nt) {
    int col = h * 64 + nt * 16 + lr;
#pragma unroll
    for (int r = 0; r < 4; ++r)
      Hout[(rowb + lh * 4 + r) * 1024 + col] = f2b(o[nt][r] * lrw[r]);
  }
}

// -------------------------------------------------- y = x + layer_norm(x)
__global__ __launch_bounds__(256) void ln_res_bf(
    const unsigned short* __restrict__ Xi, const float* __restrict__ wln,
    unsigned short* __restrict__ Y) {
  int row = blockIdx.x, tid = threadIdx.x;
  ushort4 u = ((const ushort4*)(Xi + (size_t)row * 1024))[tid];
  float x0 = b2f(u.x), x1 = b2f(u.y), x2 = b2f(u.z), x3 = b2f(u.w);
  float s = x0 + x1 + x2 + x3;
  float ss = x0 * x0 + x1 * x1 + x2 * x2 + x3 * x3;
#pragma unroll
  for (int off = 32; off; off >>= 1) {
    s += __shfl_xor(s, off);
    ss += __shfl_xor(ss, off);
  }
  __shared__ float sw[4], ssw[4];
  int wv = tid >> 6, ln = tid & 63;
  if (ln == 0) { sw[wv] = s; ssw[wv] = ss; }
  __syncthreads();
  s = sw[0] + sw[1] + sw[2] + sw[3];
  ss = ssw[0] + ssw[1] + ssw[2] + ssw[3];
  float mean = s * (1.f / 1024.f);
  float var = ss * (1.f / 1024.f) - mean * mean;
  float rstd = rsqrtf(var + 1e-5f);
  float4 wv4 = ((const float4*)wln)[tid];
  ushort4 out;
  out.x = f2b(x0 + (x0 - mean) * rstd * wv4.x);
  out.y = f2b(x1 + (x1 - mean) * rstd * wv4.y);
  out.z = f2b(x2 + (x2 - mean) * rstd * wv4.z);
  out.w = f2b(x3 + (x3 - mean) * rstd * wv4.w);
  ((ushort4*)(Y + (size_t)row * 1024))[tid] = out;
}

// ------------------------------------------- probs = softmax over T axis
__global__ __launch_bounds__(256) void softmaxT_kernel(
    const float* __restrict__ logits, float* __restrict__ probs) {
  int b = blockIdx.x / VOC;
  int v = blockIdx.x - b * VOC;
  const float* src = logits + (size_t)b * 1024 * 128 + v;
  float vals[4];
  float m = -1e30f;
#pragma unroll
  for (int i = 0; i < 4; ++i) {
    int t = threadIdx.x + 256 * i;
    vals[i] = src[(size_t)t * 128];
    m = fmaxf(m, vals[i]);
  }
#pragma unroll
  for (int off = 32; off; off >>= 1) m = fmaxf(m, __shfl_xor(m, off));
  __shared__ float sm[4], ssum[4];
  int wv = threadIdx.x >> 6, ln = threadIdx.x & 63;
  if (ln == 0) sm[wv] = m;
  __syncthreads();
  m = fmaxf(fmaxf(sm[0], sm[1]), fmaxf(sm[2], sm[3]));
  float s = 0.f;
#pragma unroll
  for (int i = 0; i < 4; ++i) { vals[i] = __expf(vals[i] - m); s += vals[i]; }
#pragma unroll
  for (int off = 32; off; off >>= 1) s += __shfl_xor(s, off);
  if (ln == 0) ssum[wv] = s;
  __syncthreads();
  s = ssum[0] + ssum[1] + ssum[2] + ssum[3];
  float inv = 1.f / s;
  float* dst = probs + (size_t)b * 1024 * VOC + v;
#pragma unroll
  for (int i = 0; i < 4; ++i) {
    int t = threadIdx.x + 256 * i;
    dst[(size_t)t * VOC] = vals[i] * inv;
  }
}

// ------------------------- per-row -log_softmax_V(probs)[target] partials
__global__ __launch_bounds__(256) void loss_rows_kernel(
    const float* __restrict__ probs, const int* __restrict__ tgt,
    float* __restrict__ partial) {
  int wv = threadIdx.x >> 6, lane = threadIdx.x & 63;
  int row = blockIdx.x * 4 + wv;
  const float* p = probs + (size_t)row * VOC;
  float x0 = p[lane];
  float x1 = (lane == 0) ? p[64] : -1e30f;
  float m = fmaxf(x0, x1);
#pragma unroll
  for (int off = 32; off; off >>= 1) m = fmaxf(m, __shfl_xor(m, off));
  float s = __expf(x0 - m) + ((lane == 0) ? __expf(x1 - m) : 0.f);
#pragma unroll
  for (int off = 32; off; off >>= 1) s += __shfl_xor(s, off);
  if (lane == 0) {
    int tg = tgt[row];
    partial[row] = (p[tg] - m) - logf(s);
  }
}

__global__ __launch_bounds__(256) void loss_final_kernel(
    const float* __restrict__ partial, float* __restrict__ out) {
  float s = 0.f;
  for (int i = threadIdx.x; i < Mrow; i += 256) s += partial[i];
#pragma unroll
  for (int off = 32; off; off >>= 1) s += __shfl_xor(s, off);
  __shared__ float sw[4];
  int wv = threadIdx.x >> 6, ln = threadIdx.x & 63;
  if (ln == 0) sw[wv] = s;
  __syncthreads();
  if (threadIdx.x == 0) out[0] = -(sw[0] + sw[1] + sw[2] + sw[3]) / (float)Mrow;
}

// ------------------------------------------------------------------ launch
extern "C" void kernel_launch(void* const* d_in, const int* in_sizes, int n_in,
                              void* d_out, int out_size, void* d_ws,
                              size_t ws_size, hipStream_t stream) {
  (void)in_sizes; (void)n_in; (void)out_size; (void)ws_size;
  const int*   tok    = (const int*)d_in[0];
  const int*   target = (const int*)d_in[1];
  const float* Wtok   = (const float*)d_in[3];
  const float* Wpos   = (const float*)d_in[4];
  const float* Wq = (const float*)d_in[5];  const float* bq = (const float*)d_in[6];
  const float* Wk = (const float*)d_in[7];  const float* bk = (const float*)d_in[8];
  const float* Wv = (const float*)d_in[9];  const float* bv = (const float*)d_in[10];
  const float* W1 = (const float*)d_in[11]; const float* b1 = (const float*)d_in[12];
  const float* W2 = (const float*)d_in[13]; const float* b2 = (const float*)d_in[14];
  const float* lnw = (const float*)d_in[15];
  const float* Wf = (const float*)d_in[16]; const float* bf = (const float*)d_in[17];
  float* out = (float*)d_out;

  char* p = (char*)d_ws;
  unsigned short* Xb    = (unsigned short*)p; p += (size_t)Mrow * 1024 * 2;
  unsigned short* QKVb  = (unsigned short*)p; p += (size_t)Mrow * 3072 * 2;
  unsigned short* Vt    = (unsigned short*)p; p += (size_t)64 * 64 * 1024 * 2;
  unsigned short* Hb    = (unsigned short*)p; p += (size_t)Mrow * 1024 * 2;
  unsigned short* F2b   = (unsigned short*)p; p += (size_t)Mrow * 1024 * 2;
  unsigned short* FF1b  = (unsigned short*)p; p += (size_t)Mrow * 4096 * 2;
  unsigned short* WqkvT = (unsigned short*)p; p += (size_t)3072 * 1024 * 2;
  unsigned short* W1T   = (unsigned short*)p; p += (size_t)4096 * 1024 * 2;
  unsigned short* W2T   = (unsigned short*)p; p += (size_t)1024 * 4096 * 2;
  unsigned short* WfT   = (unsigned short*)p; p += (size_t)128 * 1024 * 2;
  float* bqkv = (float*)p; p += 3072 * 4;
  float* bfp  = (float*)p; p += 128 * 4;
  float* LOG  = (float*)p; p += (size_t)Mrow * 128 * 4;
  float* PART = (float*)p; p += Mrow * 4;

  // weight prep (bf16, transposed to [N][K])
  wt_conv<<<dim3(32, 32), 256, 0, stream>>>(Wq, WqkvT,                1024, 1024);
  wt_conv<<<dim3(32, 32), 256, 0, stream>>>(Wk, WqkvT + 1024 * 1024,  1024, 1024);
  wt_conv<<<dim3(32, 32), 256, 0, stream>>>(Wv, WqkvT + 2048 * 1024,  1024, 1024);
  wt_conv<<<dim3(32, 128), 256, 0, stream>>>(W1, W1T, 1024, 4096);
  wt_conv<<<dim3(128, 32), 256, 0, stream>>>(W2, W2T, 4096, 1024);
  wt_conv<<<dim3(32, 4), 256, 0, stream>>>(Wf, WfT, 1024, VOC);
  bias_prep<<<13, 256, 0, stream>>>(bq, bk, bv, bf, bqkv, bfp);

  embed_bf<<<Mrow, 256, 0, stream>>>(tok, Wtok, Wpos, Xb);

  for (int l = 0; l < NL; ++l) {
    gemm_mfma<128, 128, false, false><<<dim3(32, 24), 256, 0, stream>>>(
        Xb, WqkvT, bqkv, QKVb, 3072, 1024);
    transpose_v<<<dim3(16, 64), 256, 0, stream>>>(QKVb, Vt);
    attn_mfma<<<dim3(16, 64), 256, 0, stream>>>(QKVb, Vt, Hb);
    ln_res_bf<<<Mrow, 256, 0, stream>>>(Hb, lnw, F2b);            // h + ln(h)
    gemm_mfma<128, 128, true, false><<<dim3(32, 32), 256, 0, stream>>>(
        F2b, W1T, b1, FF1b, 4096, 1024);                          // relu(hW1+b1)
    gemm_mfma<64, 128, false, false><<<dim3(64, 8), 256, 0, stream>>>(
        FF1b, W2T, b2, Hb, 1024, 4096);                           // ff2 (2 blk/CU)
    ln_res_bf<<<Mrow, 256, 0, stream>>>(Hb, lnw, Xb);             // ff + ln(ff)
  }

  gemm_mfma<64, 128, false, true><<<dim3(64, 1), 256, 0, stream>>>(
      Xb, WfT, bfp, LOG, 128, 1024);                              // logits (f32)
  softmaxT_kernel<<<4 * VOC, 256, 0, stream>>>(LOG, out + 1);
  loss_rows_kernel<<<Mrow / 4, 256, 0, stream>>>(out + 1, target, PART);
  loss_final_kernel<<<1, 256, 0, stream>>>(PART, out);
}

// Round 4
// 1167.925 us; speedup vs baseline: 13.7004x; 1.1482x over previous
//
#include <hip/hip_runtime.h>

typedef __attribute__((ext_vector_type(8))) short bh8;    // 8 bf16 = 4 VGPR
typedef __attribute__((ext_vector_type(4))) float f4v;    // MFMA acc

constexpr int VOC = 65;
constexpr int NL  = 6;
constexpr int Mrow = 4096;   // B*T

__device__ inline float b2f(unsigned short u) {
  union { unsigned int i; float f; } x; x.i = ((unsigned int)u) << 16; return x.f;
}
__device__ inline unsigned short f2b(float f) {
  union { float f; unsigned int i; } x; x.f = f;
  return (unsigned short)((x.i + 0x7FFFu + ((x.i >> 16) & 1u)) >> 16);
}
__device__ inline void gld16(const void* g, void* l) {
  __builtin_amdgcn_global_load_lds(
      (const __attribute__((address_space(1))) unsigned int*)g,
      (__attribute__((address_space(3))) unsigned int*)l, 16, 0, 0);
}
// swizzled LDS b128 read from a row-major [rows][64 bf16] tile (128 B rows)
__device__ inline bh8 lds_swz(const unsigned short* base, int row, int colbyte) {
  int off = row * 128 + (colbyte ^ ((row & 7) << 4));
  return *(const bh8*)((const char*)base + off);
}
__device__ inline f4v mfma16(bh8 a, bh8 b, f4v c) {
  return __builtin_amdgcn_mfma_f32_16x16x32_bf16(a, b, c, 0, 0, 0);
}
#define VMCNT0() asm volatile("s_waitcnt vmcnt(0)" ::: "memory")

// ---------------------------------------------------------------- weight prep
__global__ __launch_bounds__(256) void wt_conv(const float* __restrict__ src,
    unsigned short* __restrict__ dst, int K, int N) {
  __shared__ float t[32][33];
  int k0 = blockIdx.x * 32, n0 = blockIdx.y * 32;
  int tid = threadIdx.x;
#pragma unroll
  for (int i = 0; i < 4; ++i) {
    int idx = tid + i * 256;
    int kr = idx >> 5, nc = idx & 31;
    t[kr][nc] = (n0 + nc < N) ? src[(size_t)(k0 + kr) * N + n0 + nc] : 0.f;
  }
  __syncthreads();
#pragma unroll
  for (int i = 0; i < 4; ++i) {
    int idx = tid + i * 256;
    int nr = idx >> 5, kc = idx & 31;
    dst[(size_t)(n0 + nr) * K + k0 + kc] = f2b(t[kc][nr]);
  }
}

__global__ __launch_bounds__(256) void bias_prep(
    const float* __restrict__ bq, const float* __restrict__ bk,
    const float* __restrict__ bv, const float* __restrict__ bf,
    float* __restrict__ bqkv, float* __restrict__ bfp) {
  int i = blockIdx.x * 256 + threadIdx.x;
  if (i < 1024) bqkv[i] = bq[i];
  else if (i < 2048) bqkv[i] = bk[i - 1024];
  else if (i < 3072) bqkv[i] = bv[i - 2048];
  else if (i < 3200) bfp[i - 3072] = (i - 3072 < VOC) ? bf[i - 3072] : 0.f;
}

// ---------------------------------------------------------------- embedding
__global__ __launch_bounds__(256) void embed_bf(const int* __restrict__ tok,
    const float* __restrict__ Wtok, const float* __restrict__ Wpos,
    unsigned short* __restrict__ Xb) {
  int bt = blockIdx.x, t = bt & 1023, tid = threadIdx.x;
  int id = tok[bt];
  float4 a = ((const float4*)(Wtok + (size_t)id * 1024))[tid];
  float4 p = ((const float4*)(Wpos + (size_t)t * 1024))[tid];
  ushort4 o;
  o.x = f2b(a.x + p.x); o.y = f2b(a.y + p.y);
  o.z = f2b(a.z + p.z); o.w = f2b(a.w + p.w);
  ((ushort4*)(Xb + (size_t)bt * 1024))[tid] = o;
}

// ------------------------------------------------------------------- GEMM
// C[M,N] = A[M,K] @ Bt[N,K]^T + bias. 2-phase pipelined (T3-minimum):
// double-buffered LDS, stage(next) issued BEFORE compute(cur), one raw
// s_barrier per K-step with vmcnt(0) after the MFMA phase (loads hide
// under compute). Both-sides XOR swizzle as before.
template <int TM, int TN, bool RELU, bool F32OUT>
__global__ __launch_bounds__(256) void gemm_mfma(
    const unsigned short* __restrict__ A, const unsigned short* __restrict__ Bt,
    const float* __restrict__ bias, void* __restrict__ Cout, long N, long K) {
  constexpr int MI = TM / 32, NI = TN / 32;   // fragments per wave
  constexpr int ABUF = TM * 64, BBUF = TN * 64;
  __shared__ unsigned short As[2 * ABUF];
  __shared__ unsigned short Bs[2 * BBUF];
  const int tid = threadIdx.x;
  const int lane = tid & 63, w = tid >> 6;
  const int wr = w >> 1, wc = w & 1;
  const int lr = lane & 15, lh = lane >> 4;
  const long row0 = (long)blockIdx.x * TM, col0 = (long)blockIdx.y * TN;

  f4v acc[MI][NI];
#pragma unroll
  for (int i = 0; i < MI; ++i)
#pragma unroll
    for (int j = 0; j < NI; ++j) acc[i][j] = f4v{0.f, 0.f, 0.f, 0.f};

  // staging: thread covers row rg (per 32-row group), k-chunk ch = s^(rg&7)
  const int rg = tid >> 3, s = tid & 7;
  const int ch = s ^ (rg & 7);
  const unsigned short* Ap = A + (row0 + rg) * K + ch * 8;
  const unsigned short* Bp = Bt + (col0 + rg) * K + ch * 8;

  const int nt = (int)(K >> 6);
  // prologue: stage tile 0 into buffer 0
#pragma unroll
  for (int i = 0; i < MI; ++i) gld16(Ap + i * 32 * K, &As[(i * 256 + tid) * 8]);
#pragma unroll
  for (int i = 0; i < NI; ++i) gld16(Bp + i * 32 * K, &Bs[(i * 256 + tid) * 8]);
  VMCNT0();
  __builtin_amdgcn_s_barrier();

  for (int t = 0; t < nt; ++t) {
    const int cur = t & 1;
    if (t + 1 < nt) {
      const long k0 = (long)(t + 1) << 6;
      const int nb = (cur ^ 1);
#pragma unroll
      for (int i = 0; i < MI; ++i)
        gld16(Ap + i * 32 * K + k0, &As[nb * ABUF + (i * 256 + tid) * 8]);
#pragma unroll
      for (int i = 0; i < NI; ++i)
        gld16(Bp + i * 32 * K + k0, &Bs[nb * BBUF + (i * 256 + tid) * 8]);
    }
    const unsigned short* Ab = &As[cur * ABUF];
    const unsigned short* Bb = &Bs[cur * BBUF];
#pragma unroll
    for (int ks = 0; ks < 2; ++ks) {
      bh8 a[MI], b[NI];
      const int slot = ((ks << 2) | lh) ^ (lr & 7);
#pragma unroll
      for (int mi = 0; mi < MI; ++mi) {
        int m = wr * (TM / 2) + mi * 16 + lr;
        a[mi] = *(const bh8*)((const char*)Ab + m * 128 + slot * 16);
      }
#pragma unroll
      for (int ni = 0; ni < NI; ++ni) {
        int n = wc * (TN / 2) + ni * 16 + lr;
        b[ni] = *(const bh8*)((const char*)Bb + n * 128 + slot * 16);
      }
#pragma unroll
      for (int mi = 0; mi < MI; ++mi)
#pragma unroll
        for (int ni = 0; ni < NI; ++ni)
          acc[mi][ni] = mfma16(a[mi], b[ni], acc[mi][ni]);
    }
    VMCNT0();                       // next-tile loads landed (hidden by MFMA)
    __builtin_amdgcn_s_barrier();   // all waves done reading cur buffer
  }
#pragma unroll
  for (int mi = 0; mi < MI; ++mi) {
#pragma unroll
    for (int ni = 0; ni < NI; ++ni) {
      long col = col0 + wc * (TN / 2) + ni * 16 + lr;
      float bb = bias[col];
#pragma unroll
      for (int r = 0; r < 4; ++r) {
        long row = row0 + wr * (TM / 2) + mi * 16 + lh * 4 + r;
        float v = acc[mi][ni][r] + bb;
        if (RELU) v = fmaxf(v, 0.f);
        if (F32OUT) ((float*)Cout)[row * N + col] = v;
        else ((unsigned short*)Cout)[row * N + col] = f2b(v);
      }
    }
  }
}

// ------------------------------------------ V transpose: Vt[bh][dh][t] bf16
__global__ __launch_bounds__(256) void transpose_v(
    const unsigned short* __restrict__ QKV, unsigned short* __restrict__ Vt) {
  __shared__ unsigned short tile[64][80];
  int tt = blockIdx.x, bh = blockIdx.y;
  int b = bh >> 4, h = bh & 15;
  int tid = threadIdx.x;
#pragma unroll
  for (int it = 0; it < 2; ++it) {
    int idx = tid + it * 256;
    int r = idx >> 3, c8 = (idx & 7) * 8;
    uint4 d = *(const uint4*)(QKV + (size_t)(b * 1024 + tt * 64 + r) * 3072 +
                              2048 + h * 64 + c8);
    *(uint4*)&tile[r][c8] = d;
  }
  __syncthreads();
#pragma unroll
  for (int it = 0; it < 2; ++it) {
    int idx = tid + it * 256;
    int d = idx >> 3, t8 = (idx & 7) * 8;
    unsigned short tmp[8];
#pragma unroll
    for (int j = 0; j < 8; ++j) tmp[j] = tile[t8 + j][d];
    *(uint4*)(Vt + (size_t)(bh * 64 + d) * 1024 + tt * 64 + t8) = *(uint4*)tmp;
  }
}

// ------------------------------------------------- flash attention (MFMA)
// Swapped QK^T (S^T = K·Q^T): each lane owns one q-row's scores -> softmax
// is 15 in-reg fmax + 2 shfl_xor; P packed via v_cvt_pk_bf16_f32, 4x b64
// LDS writes. 2-phase double-buffered K/V staging, 1 barrier per KV tile.
__global__ __launch_bounds__(256) void attn_mfma(
    const unsigned short* __restrict__ QKV, const unsigned short* __restrict__ Vt,
    unsigned short* __restrict__ Hout) {
  __shared__ unsigned short Ks[2][64 * 64];  // [key][dh]  swizzled
  __shared__ unsigned short Vs[2][64 * 64];  // [dh][key]  swizzled
  __shared__ unsigned short Ps[4][16 * 64];  // per-wave [q][key] swizzled
  const int tid = threadIdx.x, w = tid >> 6, lane = tid & 63;
  const int qt = (int)gridDim.x - 1 - (int)blockIdx.x;   // heavy blocks first
  const int bh = blockIdx.y;
  const int b = bh >> 4, h = bh & 15;
  const int lr = lane & 15, lh = lane >> 4, lh4 = lh * 4;

  // Q fragments, register-resident (lane holds Q row w*16+lr)
  const unsigned short* qp =
      QKV + (size_t)(b * 1024 + qt * 64 + w * 16 + lr) * 3072 + h * 64 + lh * 8;
  bh8 aq0 = *(const bh8*)qp;
  bh8 aq1 = *(const bh8*)(qp + 32);

  f4v o[4];
#pragma unroll
  for (int i = 0; i < 4; ++i) o[i] = f4v{0.f, 0.f, 0.f, 0.f};
  float m = -1e30f, l = 0.f;   // online stats for q-row (w*16 + lr)

  const int r8 = tid >> 3, slot = tid & 7;
  unsigned short* pw = &Ps[w][0];

  auto stage = [&](int kt, int buf) {
    int r = r8, c8 = (slot ^ (r & 7)) * 8;
    gld16(QKV + (size_t)(b * 1024 + kt * 64 + r) * 3072 + 1024 + h * 64 + c8,
          &Ks[buf][tid * 8]);
    gld16(Vt + (size_t)(bh * 64 + r) * 1024 + kt * 64 + c8, &Vs[buf][tid * 8]);
    r = r8 + 32; c8 = (slot ^ (r & 7)) * 8;
    gld16(QKV + (size_t)(b * 1024 + kt * 64 + r) * 3072 + 1024 + h * 64 + c8,
          &Ks[buf][2048 + tid * 8]);
    gld16(Vt + (size_t)(bh * 64 + r) * 1024 + kt * 64 + c8,
          &Vs[buf][2048 + tid * 8]);
  };

  stage(0, 0);
  VMCNT0();
  __builtin_amdgcn_s_barrier();

  for (int kt = 0; kt <= qt; ++kt) {
    const int cur = kt & 1;
    if (kt < qt) stage(kt + 1, cur ^ 1);

    // S^T = K Q^T : s[nt][r] = S[key=nt*16+lh4+r][q=lr] (within tiles)
    f4v s[4];
#pragma unroll
    for (int nt = 0; nt < 4; ++nt) {
      bh8 k0 = lds_swz(Ks[cur], nt * 16 + lr, lh * 16);
      bh8 k1 = lds_swz(Ks[cur], nt * 16 + lr, lh * 16 + 64);
      f4v z = f4v{0.f, 0.f, 0.f, 0.f};
      z = mfma16(k0, aq0, z);
      z = mfma16(k1, aq1, z);
      s[nt] = z;
    }
    const bool diag = (kt == qt);
    const int qloc = w * 16 + lr;
#pragma unroll
    for (int nt = 0; nt < 4; ++nt)
#pragma unroll
      for (int r = 0; r < 4; ++r) {
        float v = s[nt][r] * 0.03125f;
        if (diag && (nt * 16 + lh4 + r) > qloc) v = -1e30f;
        s[nt][r] = v;
      }
    // row stats: 16 values per lane, reduce across the 4 lanes sharing lr
    float tm = s[0][0];
#pragma unroll
    for (int nt = 0; nt < 4; ++nt)
#pragma unroll
      for (int r = 0; r < 4; ++r) tm = fmaxf(tm, s[nt][r]);
    tm = fmaxf(tm, __shfl_xor(tm, 16));
    tm = fmaxf(tm, __shfl_xor(tm, 32));
    float mn = fmaxf(m, tm);
    float corr = __expf(m - mn);
    m = mn;
    float sum = 0.f;
#pragma unroll
    for (int nt = 0; nt < 4; ++nt)
#pragma unroll
      for (int r = 0; r < 4; ++r) {
        float e = __expf(s[nt][r] - mn);
        s[nt][r] = e;
        sum += e;
      }
    sum += __shfl_xor(sum, 16);
    sum += __shfl_xor(sum, 32);
    l = l * corr + sum;
    // P -> per-wave LDS in A-layout (row = q-local = lr), packed b64 writes
#pragma unroll
    for (int nt = 0; nt < 4; ++nt) {
      unsigned int u0, u1;
      asm("v_cvt_pk_bf16_f32 %0, %1, %2" : "=v"(u0) : "v"(s[nt][0]), "v"(s[nt][1]));
      asm("v_cvt_pk_bf16_f32 %0, %1, %2" : "=v"(u1) : "v"(s[nt][2]), "v"(s[nt][3]));
      uint2 pk{u0, u1};
      *(uint2*)((char*)pw + lr * 128 + ((nt * 32 + lh * 8) ^ ((lr & 7) << 4))) = pk;
    }
    // corr is per q=lr; O rows are q=lh4+r -> broadcast via shfl
    float c0 = __shfl(corr, lh4 + 0), c1 = __shfl(corr, lh4 + 1);
    float c2 = __shfl(corr, lh4 + 2), c3 = __shfl(corr, lh4 + 3);
#pragma unroll
    for (int nt = 0; nt < 4; ++nt) {
      o[nt][0] *= c0; o[nt][1] *= c1; o[nt][2] *= c2; o[nt][3] *= c3;
    }
    bh8 pa0 = lds_swz(pw, lr, lh * 16);
    bh8 pa1 = lds_swz(pw, lr, lh * 16 + 64);
#pragma unroll
    for (int nt = 0; nt < 4; ++nt) {
      bh8 v0 = lds_swz(Vs[cur], nt * 16 + lr, lh * 16);
      bh8 v1 = lds_swz(Vs[cur], nt * 16 + lr, lh * 16 + 64);
      o[nt] = mfma16(pa0, v0, o[nt]);
      o[nt] = mfma16(pa1, v1, o[nt]);
    }
    VMCNT0();                       // next K/V tiles landed (hidden by compute)
    __builtin_amdgcn_s_barrier();
  }
  // epilogue
  float linv = 1.f / l;
  float l0 = __shfl(linv, lh4 + 0), l1 = __shfl(linv, lh4 + 1);
  float l2 = __shfl(linv, lh4 + 2), l3 = __shfl(linv, lh4 + 3);
  const size_t rowb = (size_t)(b * 1024 + qt * 64 + w * 16);
#pragma unroll
  for (int nt = 0; nt < 4; ++nt) {
    int col = h * 64 + nt * 16 + lr;
    Hout[(rowb + lh4 + 0) * 1024 + col] = f2b(o[nt][0] * l0);
    Hout[(rowb + lh4 + 1) * 1024 + col] = f2b(o[nt][1] * l1);
    Hout[(rowb + lh4 + 2) * 1024 + col] = f2b(o[nt][2] * l2);
    Hout[(rowb + lh4 + 3) * 1024 + col] = f2b(o[nt][3] * l3);
  }
}

// -------------------------------------------------- y = x + layer_norm(x)
__global__ __launch_bounds__(256) void ln_res_bf(
    const unsigned short* __restrict__ Xi, const float* __restrict__ wln,
    unsigned short* __restrict__ Y) {
  int row = blockIdx.x, tid = threadIdx.x;
  ushort4 u = ((const ushort4*)(Xi + (size_t)row * 1024))[tid];
  float x0 = b2f(u.x), x1 = b2f(u.y), x2 = b2f(u.z), x3 = b2f(u.w);
  float s = x0 + x1 + x2 + x3;
  float ss = x0 * x0 + x1 * x1 + x2 * x2 + x3 * x3;
#pragma unroll
  for (int off = 32; off; off >>= 1) {
    s += __shfl_xor(s, off);
    ss += __shfl_xor(ss, off);
  }
  __shared__ float sw[4], ssw[4];
  int wv = tid >> 6, ln = tid & 63;
  if (ln == 0) { sw[wv] = s; ssw[wv] = ss; }
  __syncthreads();
  s = sw[0] + sw[1] + sw[2] + sw[3];
  ss = ssw[0] + ssw[1] + ssw[2] + ssw[3];
  float mean = s * (1.f / 1024.f);
  float var = ss * (1.f / 1024.f) - mean * mean;
  float rstd = rsqrtf(var + 1e-5f);
  float4 wv4 = ((const float4*)wln)[tid];
  ushort4 out;
  out.x = f2b(x0 + (x0 - mean) * rstd * wv4.x);
  out.y = f2b(x1 + (x1 - mean) * rstd * wv4.y);
  out.z = f2b(x2 + (x2 - mean) * rstd * wv4.z);
  out.w = f2b(x3 + (x3 - mean) * rstd * wv4.w);
  ((ushort4*)(Y + (size_t)row * 1024))[tid] = out;
}

// ------------------------------------------- probs = softmax over T axis
__global__ __launch_bounds__(256) void softmaxT_kernel(
    const float* __restrict__ logits, float* __restrict__ probs) {
  int b = blockIdx.x / VOC;
  int v = blockIdx.x - b * VOC;
  const float* src = logits + (size_t)b * 1024 * 128 + v;
  float vals[4];
  float m = -1e30f;
#pragma unroll
  for (int i = 0; i < 4; ++i) {
    int t = threadIdx.x + 256 * i;
    vals[i] = src[(size_t)t * 128];
    m = fmaxf(m, vals[i]);
  }
#pragma unroll
  for (int off = 32; off; off >>= 1) m = fmaxf(m, __shfl_xor(m, off));
  __shared__ float sm[4], ssum[4];
  int wv = threadIdx.x >> 6, ln = threadIdx.x & 63;
  if (ln == 0) sm[wv] = m;
  __syncthreads();
  m = fmaxf(fmaxf(sm[0], sm[1]), fmaxf(sm[2], sm[3]));
  float s = 0.f;
#pragma unroll
  for (int i = 0; i < 4; ++i) { vals[i] = __expf(vals[i] - m); s += vals[i]; }
#pragma unroll
  for (int off = 32; off; off >>= 1) s += __shfl_xor(s, off);
  if (ln == 0) ssum[wv] = s;
  __syncthreads();
  s = ssum[0] + ssum[1] + ssum[2] + ssum[3];
  float inv = 1.f / s;
  float* dst = probs + (size_t)b * 1024 * VOC + v;
#pragma unroll
  for (int i = 0; i < 4; ++i) {
    int t = threadIdx.x + 256 * i;
    dst[(size_t)t * VOC] = vals[i] * inv;
  }
}

// ------------------------- per-row -log_softmax_V(probs)[target] partials
__global__ __launch_bounds__(256) void loss_rows_kernel(
    const float* __restrict__ probs, const int* __restrict__ tgt,
    float* __restrict__ partial) {
  int wv = threadIdx.x >> 6, lane = threadIdx.x & 63;
  int row = blockIdx.x * 4 + wv;
  const float* p = probs + (size_t)row * VOC;
  float x0 = p[lane];
  float x1 = (lane == 0) ? p[64] : -1e30f;
  float m = fmaxf(x0, x1);
#pragma unroll
  for (int off = 32; off; off >>= 1) m = fmaxf(m, __shfl_xor(m, off));
  float s = __expf(x0 - m) + ((lane == 0) ? __expf(x1 - m) : 0.f);
#pragma unroll
  for (int off = 32; off; off >>= 1) s += __shfl_xor(s, off);
  if (lane == 0) {
    int tg = tgt[row];
    partial[row] = (p[tg] - m) - logf(s);
  }
}

__global__ __launch_bounds__(256) void loss_final_kernel(
    const float* __restrict__ partial, float* __restrict__ out) {
  float s = 0.f;
  for (int i = threadIdx.x; i < Mrow; i += 256) s += partial[i];
#pragma unroll
  for (int off = 32; off; off >>= 1) s += __shfl_xor(s, off);
  __shared__ float sw[4];
  int wv = threadIdx.x >> 6, ln = threadIdx.x & 63;
  if (ln == 0) sw[wv] = s;
  __syncthreads();
  if (threadIdx.x == 0) out[0] = -(sw[0] + sw[1] + sw[2] + sw[3]) / (float)Mrow;
}

// ------------------------------------------------------------------ launch
extern "C" void kernel_launch(void* const* d_in, const int* in_sizes, int n_in,
                              void* d_out, int out_size, void* d_ws,
                              size_t ws_size, hipStream_t stream) {
  (void)in_sizes; (void)n_in; (void)out_size; (void)ws_size;
  const int*   tok    = (const int*)d_in[0];
  const int*   target = (const int*)d_in[1];
  const float* Wtok   = (const float*)d_in[3];
  const float* Wpos   = (const float*)d_in[4];
  const float* Wq = (const float*)d_in[5];  const float* bq = (const float*)d_in[6];
  const float* Wk = (const float*)d_in[7];  const float* bk = (const float*)d_in[8];
  const float* Wv = (const float*)d_in[9];  const float* bv = (const float*)d_in[10];
  const float* W1 = (const float*)d_in[11]; const float* b1 = (const float*)d_in[12];
  const float* W2 = (const float*)d_in[13]; const float* b2 = (const float*)d_in[14];
  const float* lnw = (const float*)d_in[15];
  const float* Wf = (const float*)d_in[16]; const float* bf = (const float*)d_in[17];
  float* out = (float*)d_out;

  char* p = (char*)d_ws;
  unsigned short* Xb    = (unsigned short*)p; p += (size_t)Mrow * 1024 * 2;
  unsigned short* QKVb  = (unsigned short*)p; p += (size_t)Mrow * 3072 * 2;
  unsigned short* Vt    = (unsigned short*)p; p += (size_t)64 * 64 * 1024 * 2;
  unsigned short* Hb    = (unsigned short*)p; p += (size_t)Mrow * 1024 * 2;
  unsigned short* F2b   = (unsigned short*)p; p += (size_t)Mrow * 1024 * 2;
  unsigned short* FF1b  = (unsigned short*)p; p += (size_t)Mrow * 4096 * 2;
  unsigned short* WqkvT = (unsigned short*)p; p += (size_t)3072 * 1024 * 2;
  unsigned short* W1T   = (unsigned short*)p; p += (size_t)4096 * 1024 * 2;
  unsigned short* W2T   = (unsigned short*)p; p += (size_t)1024 * 4096 * 2;
  unsigned short* WfT   = (unsigned short*)p; p += (size_t)128 * 1024 * 2;
  float* bqkv = (float*)p; p += 3072 * 4;
  float* bfp  = (float*)p; p += 128 * 4;
  float* LOG  = (float*)p; p += (size_t)Mrow * 128 * 4;
  float* PART = (float*)p; p += Mrow * 4;

  wt_conv<<<dim3(32, 32), 256, 0, stream>>>(Wq, WqkvT,                1024, 1024);
  wt_conv<<<dim3(32, 32), 256, 0, stream>>>(Wk, WqkvT + 1024 * 1024,  1024, 1024);
  wt_conv<<<dim3(32, 32), 256, 0, stream>>>(Wv, WqkvT + 2048 * 1024,  1024, 1024);
  wt_conv<<<dim3(32, 128), 256, 0, stream>>>(W1, W1T, 1024, 4096);
  wt_conv<<<dim3(128, 32), 256, 0, stream>>>(W2, W2T, 4096, 1024);
  wt_conv<<<dim3(32, 4), 256, 0, stream>>>(Wf, WfT, 1024, VOC);
  bias_prep<<<13, 256, 0, stream>>>(bq, bk, bv, bf, bqkv, bfp);

  embed_bf<<<Mrow, 256, 0, stream>>>(tok, Wtok, Wpos, Xb);

  for (int l = 0; l < NL; ++l) {
    gemm_mfma<128, 128, false, false><<<dim3(32, 24), 256, 0, stream>>>(
        Xb, WqkvT, bqkv, QKVb, 3072, 1024);
    transpose_v<<<dim3(16, 64), 256, 0, stream>>>(QKVb, Vt);
    attn_mfma<<<dim3(16, 64), 256, 0, stream>>>(QKVb, Vt, Hb);
    ln_res_bf<<<Mrow, 256, 0, stream>>>(Hb, lnw, F2b);            // h + ln(h)
    gemm_mfma<128, 128, true, false><<<dim3(32, 32), 256, 0, stream>>>(
        F2b, W1T, b1, FF1b, 4096, 1024);                          // relu(hW1+b1)
    gemm_mfma<64, 128, false, false><<<dim3(64, 8), 256, 0, stream>>>(
        FF1b, W2T, b2, Hb, 1024, 4096);                           // ff2
    ln_res_bf<<<Mrow, 256, 0, stream>>>(Hb, lnw, Xb);             // ff + ln(ff)
  }

  gemm_mfma<64, 128, false, true><<<dim3(64, 1), 256, 0, stream>>>(
      Xb, WfT, bfp, LOG, 128, 1024);                              // logits (f32)
  softmaxT_kernel<<<4 * VOC, 256, 0, stream>>>(LOG, out + 1);
  loss_rows_kernel<<<Mrow / 4, 256, 0, stream>>>(out + 1, target, PART);
  loss_final_kernel<<<1, 256, 0, stream>>>(PART, out);
}

// Round 5
// 1104.085 us; speedup vs baseline: 14.4926x; 1.0578x over previous
//
#include <hip/hip_runtime.h>

typedef __attribute__((ext_vector_type(8))) short bh8;    // 8 bf16 = 4 VGPR
typedef __attribute__((ext_vector_type(4))) float f4v;    // MFMA acc

constexpr int VOC = 65;
constexpr int NL  = 6;
constexpr int Mrow = 4096;   // B*T

__device__ inline float b2f(unsigned short u) {
  union { unsigned int i; float f; } x; x.i = ((unsigned int)u) << 16; return x.f;
}
__device__ inline unsigned short f2b(float f) {
  union { float f; unsigned int i; } x; x.f = f;
  return (unsigned short)((x.i + 0x7FFFu + ((x.i >> 16) & 1u)) >> 16);
}
__device__ inline void gld16(const void* g, void* l) {
  __builtin_amdgcn_global_load_lds(
      (const __attribute__((address_space(1))) unsigned int*)g,
      (__attribute__((address_space(3))) unsigned int*)l, 16, 0, 0);
}
// swizzled LDS b128 read from a row-major [rows][64 bf16] tile (128 B rows)
__device__ inline bh8 lds_swz(const unsigned short* base, int row, int colbyte) {
  int off = row * 128 + (colbyte ^ ((row & 7) << 4));
  return *(const bh8*)((const char*)base + off);
}
__device__ inline f4v mfma16(bh8 a, bh8 b, f4v c) {
  return __builtin_amdgcn_mfma_f32_16x16x32_bf16(a, b, c, 0, 0, 0);
}
#define VMCNT(n) asm volatile("s_waitcnt vmcnt(" #n ")" ::: "memory")

// ---------------------------------------------------------------- weight prep
__global__ __launch_bounds__(256) void wt_conv(const float* __restrict__ src,
    unsigned short* __restrict__ dst, int K, int N) {
  __shared__ float t[32][33];
  int k0 = blockIdx.x * 32, n0 = blockIdx.y * 32;
  int tid = threadIdx.x;
#pragma unroll
  for (int i = 0; i < 4; ++i) {
    int idx = tid + i * 256;
    int kr = idx >> 5, nc = idx & 31;
    t[kr][nc] = (n0 + nc < N) ? src[(size_t)(k0 + kr) * N + n0 + nc] : 0.f;
  }
  __syncthreads();
#pragma unroll
  for (int i = 0; i < 4; ++i) {
    int idx = tid + i * 256;
    int nr = idx >> 5, kc = idx & 31;
    dst[(size_t)(n0 + nr) * K + k0 + kc] = f2b(t[kc][nr]);
  }
}

__global__ __launch_bounds__(256) void bias_prep(
    const float* __restrict__ bq, const float* __restrict__ bk,
    const float* __restrict__ bv, const float* __restrict__ bf,
    float* __restrict__ bqkv, float* __restrict__ bfp) {
  int i = blockIdx.x * 256 + threadIdx.x;
  if (i < 1024) bqkv[i] = bq[i];
  else if (i < 2048) bqkv[i] = bk[i - 1024];
  else if (i < 3072) bqkv[i] = bv[i - 2048];
  else if (i < 3200) bfp[i - 3072] = (i - 3072 < VOC) ? bf[i - 3072] : 0.f;
}

// ---------------------------------------------------------------- embedding
__global__ __launch_bounds__(256) void embed_bf(const int* __restrict__ tok,
    const float* __restrict__ Wtok, const float* __restrict__ Wpos,
    unsigned short* __restrict__ Xb) {
  int bt = blockIdx.x, t = bt & 1023, tid = threadIdx.x;
  int id = tok[bt];
  float4 a = ((const float4*)(Wtok + (size_t)id * 1024))[tid];
  float4 p = ((const float4*)(Wpos + (size_t)t * 1024))[tid];
  ushort4 o;
  o.x = f2b(a.x + p.x); o.y = f2b(a.y + p.y);
  o.z = f2b(a.z + p.z); o.w = f2b(a.w + p.w);
  ((ushort4*)(Xb + (size_t)bt * 1024))[tid] = o;
}

// ------------------------------------------------------------------- GEMM
// C[M,N] = A[M,K] @ Bt[N,K]^T + bias. 2-phase double-buffered with COUNTED
// vmcnt (T4): stage(t+1) issued, then wait only for stage(t)'s loads (the
// newer ones stay in flight across both barriers). Never vmcnt(0) in loop.
// Both-sides XOR swizzle. VT: blocks with col0>=2048 write the V part
// transposed into Vt[bh][dh][t] (4 acc rows = 4 consecutive t -> ushort4).
template <int TM, int TN, bool RELU, bool F32OUT, bool VT>
__global__ __launch_bounds__(256) void gemm_mfma(
    const unsigned short* __restrict__ A, const unsigned short* __restrict__ Bt,
    const float* __restrict__ bias, void* __restrict__ Cout,
    unsigned short* __restrict__ Vtout, long N, long K) {
  constexpr int MI = TM / 32, NI = TN / 32;   // fragments per wave
  constexpr int LNUM = MI + NI;               // gld16 per stage
  constexpr int ABUF = TM * 64, BBUF = TN * 64;
  __shared__ unsigned short As[2 * ABUF];
  __shared__ unsigned short Bs[2 * BBUF];
  const int tid = threadIdx.x;
  const int lane = tid & 63, w = tid >> 6;
  const int wr = w >> 1, wc = w & 1;
  const int lr = lane & 15, lh = lane >> 4, lh4 = lh * 4;
  const long row0 = (long)blockIdx.x * TM, col0 = (long)blockIdx.y * TN;

  f4v acc[MI][NI];
#pragma unroll
  for (int i = 0; i < MI; ++i)
#pragma unroll
    for (int j = 0; j < NI; ++j) acc[i][j] = f4v{0.f, 0.f, 0.f, 0.f};

  // staging: thread covers row rg (per 32-row group), k-chunk ch = s^(rg&7)
  const int rg = tid >> 3, s = tid & 7;
  const int ch = s ^ (rg & 7);
  const unsigned short* Ap = A + (row0 + rg) * K + ch * 8;
  const unsigned short* Bp = Bt + (col0 + rg) * K + ch * 8;

  auto stage = [&](int t, int buf) {
    const long k0 = (long)t << 6;
#pragma unroll
    for (int i = 0; i < MI; ++i)
      gld16(Ap + i * 32 * K + k0, &As[buf * ABUF + (i * 256 + tid) * 8]);
#pragma unroll
    for (int i = 0; i < NI; ++i)
      gld16(Bp + i * 32 * K + k0, &Bs[buf * BBUF + (i * 256 + tid) * 8]);
  };

  const int nt = (int)(K >> 6);
  stage(0, 0);

  for (int t = 0; t < nt; ++t) {
    const int cur = t & 1;
    if (t + 1 < nt) {
      stage(t + 1, cur ^ 1);
      if (LNUM == 8) { VMCNT(8); } else { VMCNT(6); }   // stage(t) landed
    } else {
      VMCNT(0);
    }
    __builtin_amdgcn_s_barrier();
    const unsigned short* Ab = &As[cur * ABUF];
    const unsigned short* Bb = &Bs[cur * BBUF];
#pragma unroll
    for (int ks = 0; ks < 2; ++ks) {
      bh8 a[MI], b[NI];
      const int slot = ((ks << 2) | lh) ^ (lr & 7);
#pragma unroll
      for (int mi = 0; mi < MI; ++mi) {
        int m = wr * (TM / 2) + mi * 16 + lr;
        a[mi] = *(const bh8*)((const char*)Ab + m * 128 + slot * 16);
      }
#pragma unroll
      for (int ni = 0; ni < NI; ++ni) {
        int n = wc * (TN / 2) + ni * 16 + lr;
        b[ni] = *(const bh8*)((const char*)Bb + n * 128 + slot * 16);
      }
#pragma unroll
      for (int mi = 0; mi < MI; ++mi)
#pragma unroll
        for (int ni = 0; ni < NI; ++ni)
          acc[mi][ni] = mfma16(a[mi], b[ni], acc[mi][ni]);
    }
    __builtin_amdgcn_s_barrier();   // all waves done reading cur buffer
  }

  if (VT && col0 >= 2048) {
    // V part -> Vt[(b*16+h)*64+dh][t] transposed store, 4 t's contiguous
#pragma unroll
    for (int mi = 0; mi < MI; ++mi) {
#pragma unroll
      for (int ni = 0; ni < NI; ++ni) {
        long col = col0 + wc * (TN / 2) + ni * 16 + lr;
        float bb = bias[col];
        int cc = (int)col - 2048;                 // h*64 + dh
        long row = row0 + wr * (TM / 2) + mi * 16 + lh4;
        int bi = (int)(row >> 10), tt = (int)(row & 1023);
        ushort4 o;
        o.x = f2b(acc[mi][ni][0] + bb);
        o.y = f2b(acc[mi][ni][1] + bb);
        o.z = f2b(acc[mi][ni][2] + bb);
        o.w = f2b(acc[mi][ni][3] + bb);
        *(ushort4*)&Vtout[((size_t)(bi * 16 + (cc >> 6)) * 64 + (cc & 63)) *
                              1024 + tt] = o;
      }
    }
    return;
  }
#pragma unroll
  for (int mi = 0; mi < MI; ++mi) {
#pragma unroll
    for (int ni = 0; ni < NI; ++ni) {
      long col = col0 + wc * (TN / 2) + ni * 16 + lr;
      float bb = bias[col];
#pragma unroll
      for (int r = 0; r < 4; ++r) {
        long row = row0 + wr * (TM / 2) + mi * 16 + lh4 + r;
        float v = acc[mi][ni][r] + bb;
        if (RELU) v = fmaxf(v, 0.f);
        if (F32OUT) ((float*)Cout)[row * N + col] = v;
        else ((unsigned short*)Cout)[row * N + col] = f2b(v);
      }
    }
  }
}

// ------------------------------------------------- flash attention (MFMA)
// Swapped QK^T (S^T = K·Q^T); counted-vmcnt 2-phase K/V staging.
__global__ __launch_bounds__(256) void attn_mfma(
    const unsigned short* __restrict__ QKV, const unsigned short* __restrict__ Vt,
    unsigned short* __restrict__ Hout) {
  __shared__ unsigned short Ks[2][64 * 64];  // [key][dh]  swizzled
  __shared__ unsigned short Vs[2][64 * 64];  // [dh][key]  swizzled
  __shared__ unsigned short Ps[4][16 * 64];  // per-wave [q][key] swizzled
  const int tid = threadIdx.x, w = tid >> 6, lane = tid & 63;
  const int qt = (int)gridDim.x - 1 - (int)blockIdx.x;   // heavy blocks first
  const int bh = blockIdx.y;
  const int b = bh >> 4, h = bh & 15;
  const int lr = lane & 15, lh = lane >> 4, lh4 = lh * 4;

  // Q fragments, register-resident (lane holds Q row w*16+lr)
  const unsigned short* qp =
      QKV + (size_t)(b * 1024 + qt * 64 + w * 16 + lr) * 3072 + h * 64 + lh * 8;
  bh8 aq0 = *(const bh8*)qp;
  bh8 aq1 = *(const bh8*)(qp + 32);

  f4v o[4];
#pragma unroll
  for (int i = 0; i < 4; ++i) o[i] = f4v{0.f, 0.f, 0.f, 0.f};
  float m = -1e30f, l = 0.f;   // online stats for q-row (w*16 + lr)

  const int r8 = tid >> 3, slot = tid & 7;
  unsigned short* pw = &Ps[w][0];

  auto stage = [&](int kt, int buf) {
    int r = r8, c8 = (slot ^ (r & 7)) * 8;
    gld16(QKV + (size_t)(b * 1024 + kt * 64 + r) * 3072 + 1024 + h * 64 + c8,
          &Ks[buf][tid * 8]);
    gld16(Vt + (size_t)(bh * 64 + r) * 1024 + kt * 64 + c8, &Vs[buf][tid * 8]);
    r = r8 + 32; c8 = (slot ^ (r & 7)) * 8;
    gld16(QKV + (size_t)(b * 1024 + kt * 64 + r) * 3072 + 1024 + h * 64 + c8,
          &Ks[buf][2048 + tid * 8]);
    gld16(Vt + (size_t)(bh * 64 + r) * 1024 + kt * 64 + c8,
          &Vs[buf][2048 + tid * 8]);
  };

  stage(0, 0);

  for (int kt = 0; kt <= qt; ++kt) {
    const int cur = kt & 1;
    if (kt < qt) {
      stage(kt + 1, cur ^ 1);
      VMCNT(4);                 // stage(kt) landed; stage(kt+1) in flight
    } else {
      VMCNT(0);
    }
    __builtin_amdgcn_s_barrier();

    // S^T = K Q^T : s[nt][r] = S[key=nt*16+lh4+r][q=lr] (within tiles)
    f4v s[4];
#pragma unroll
    for (int nt = 0; nt < 4; ++nt) {
      bh8 k0 = lds_swz(Ks[cur], nt * 16 + lr, lh * 16);
      bh8 k1 = lds_swz(Ks[cur], nt * 16 + lr, lh * 16 + 64);
      f4v z = f4v{0.f, 0.f, 0.f, 0.f};
      z = mfma16(k0, aq0, z);
      z = mfma16(k1, aq1, z);
      s[nt] = z;
    }
    const bool diag = (kt == qt);
    const int qloc = w * 16 + lr;
#pragma unroll
    for (int nt = 0; nt < 4; ++nt)
#pragma unroll
      for (int r = 0; r < 4; ++r) {
        float v = s[nt][r] * 0.03125f;
        if (diag && (nt * 16 + lh4 + r) > qloc) v = -1e30f;
        s[nt][r] = v;
      }
    // row stats: 16 values per lane, reduce across the 4 lanes sharing lr
    float tm = s[0][0];
#pragma unroll
    for (int nt = 0; nt < 4; ++nt)
#pragma unroll
      for (int r = 0; r < 4; ++r) tm = fmaxf(tm, s[nt][r]);
    tm = fmaxf(tm, __shfl_xor(tm, 16));
    tm = fmaxf(tm, __shfl_xor(tm, 32));
    float mn = fmaxf(m, tm);
    float corr = __expf(m - mn);
    m = mn;
    float sum = 0.f;
#pragma unroll
    for (int nt = 0; nt < 4; ++nt)
#pragma unroll
      for (int r = 0; r < 4; ++r) {
        float e = __expf(s[nt][r] - mn);
        s[nt][r] = e;
        sum += e;
      }
    sum += __shfl_xor(sum, 16);
    sum += __shfl_xor(sum, 32);
    l = l * corr + sum;
    // P -> per-wave LDS in A-layout (row = q-local = lr), packed b64 writes
#pragma unroll
    for (int nt = 0; nt < 4; ++nt) {
      unsigned int u0, u1;
      asm("v_cvt_pk_bf16_f32 %0, %1, %2" : "=v"(u0) : "v"(s[nt][0]), "v"(s[nt][1]));
      asm("v_cvt_pk_bf16_f32 %0, %1, %2" : "=v"(u1) : "v"(s[nt][2]), "v"(s[nt][3]));
      uint2 pk{u0, u1};
      *(uint2*)((char*)pw + lr * 128 + ((nt * 32 + lh * 8) ^ ((lr & 7) << 4))) = pk;
    }
    // corr is per q=lr; O rows are q=lh4+r -> broadcast via shfl
    float c0 = __shfl(corr, lh4 + 0), c1 = __shfl(corr, lh4 + 1);
    float c2 = __shfl(corr, lh4 + 2), c3 = __shfl(corr, lh4 + 3);
#pragma unroll
    for (int nt = 0; nt < 4; ++nt) {
      o[nt][0] *= c0; o[nt][1] *= c1; o[nt][2] *= c2; o[nt][3] *= c3;
    }
    bh8 pa0 = lds_swz(pw, lr, lh * 16);
    bh8 pa1 = lds_swz(pw, lr, lh * 16 + 64);
#pragma unroll
    for (int nt = 0; nt < 4; ++nt) {
      bh8 v0 = lds_swz(Vs[cur], nt * 16 + lr, lh * 16);
      bh8 v1 = lds_swz(Vs[cur], nt * 16 + lr, lh * 16 + 64);
      o[nt] = mfma16(pa0, v0, o[nt]);
      o[nt] = mfma16(pa1, v1, o[nt]);
    }
    __builtin_amdgcn_s_barrier();
  }
  // epilogue
  float linv = 1.f / l;
  float l0 = __shfl(linv, lh4 + 0), l1 = __shfl(linv, lh4 + 1);
  float l2 = __shfl(linv, lh4 + 2), l3 = __shfl(linv, lh4 + 3);
  const size_t rowb = (size_t)(b * 1024 + qt * 64 + w * 16);
#pragma unroll
  for (int nt = 0; nt < 4; ++nt) {
    int col = h * 64 + nt * 16 + lr;
    Hout[(rowb + lh4 + 0) * 1024 + col] = f2b(o[nt][0] * l0);
    Hout[(rowb + lh4 + 1) * 1024 + col] = f2b(o[nt][1] * l1);
    Hout[(rowb + lh4 + 2) * 1024 + col] = f2b(o[nt][2] * l2);
    Hout[(rowb + lh4 + 3) * 1024 + col] = f2b(o[nt][3] * l3);
  }
}

// -------------------------------------------------- y = x + layer_norm(x)
__global__ __launch_bounds__(256) void ln_res_bf(
    const unsigned short* __restrict__ Xi, const float* __restrict__ wln,
    unsigned short* __restrict__ Y) {
  int row = blockIdx.x, tid = threadIdx.x;
  ushort4 u = ((const ushort4*)(Xi + (size_t)row * 1024))[tid];
  float x0 = b2f(u.x), x1 = b2f(u.y), x2 = b2f(u.z), x3 = b2f(u.w);
  float s = x0 + x1 + x2 + x3;
  float ss = x0 * x0 + x1 * x1 + x2 * x2 + x3 * x3;
#pragma unroll
  for (int off = 32; off; off >>= 1) {
    s += __shfl_xor(s, off);
    ss += __shfl_xor(ss, off);
  }
  __shared__ float sw[4], ssw[4];
  int wv = tid >> 6, ln = tid & 63;
  if (ln == 0) { sw[wv] = s; ssw[wv] = ss; }
  __syncthreads();
  s = sw[0] + sw[1] + sw[2] + sw[3];
  ss = ssw[0] + ssw[1] + ssw[2] + ssw[3];
  float mean = s * (1.f / 1024.f);
  float var = ss * (1.f / 1024.f) - mean * mean;
  float rstd = rsqrtf(var + 1e-5f);
  float4 wv4 = ((const float4*)wln)[tid];
  ushort4 out;
  out.x = f2b(x0 + (x0 - mean) * rstd * wv4.x);
  out.y = f2b(x1 + (x1 - mean) * rstd * wv4.y);
  out.z = f2b(x2 + (x2 - mean) * rstd * wv4.z);
  out.w = f2b(x3 + (x3 - mean) * rstd * wv4.w);
  ((ushort4*)(Y + (size_t)row * 1024))[tid] = out;
}

// ------------------------------------------- probs = softmax over T axis
__global__ __launch_bounds__(256) void softmaxT_kernel(
    const float* __restrict__ logits, float* __restrict__ probs) {
  int b = blockIdx.x / VOC;
  int v = blockIdx.x - b * VOC;
  const float* src = logits + (size_t)b * 1024 * 128 + v;
  float vals[4];
  float m = -1e30f;
#pragma unroll
  for (int i = 0; i < 4; ++i) {
    int t = threadIdx.x + 256 * i;
    vals[i] = src[(size_t)t * 128];
    m = fmaxf(m, vals[i]);
  }
#pragma unroll
  for (int off = 32; off; off >>= 1) m = fmaxf(m, __shfl_xor(m, off));
  __shared__ float sm[4], ssum[4];
  int wv = threadIdx.x >> 6, ln = threadIdx.x & 63;
  if (ln == 0) sm[wv] = m;
  __syncthreads();
  m = fmaxf(fmaxf(sm[0], sm[1]), fmaxf(sm[2], sm[3]));
  float s = 0.f;
#pragma unroll
  for (int i = 0; i < 4; ++i) { vals[i] = __expf(vals[i] - m); s += vals[i]; }
#pragma unroll
  for (int off = 32; off; off >>= 1) s += __shfl_xor(s, off);
  if (ln == 0) ssum[wv] = s;
  __syncthreads();
  s = ssum[0] + ssum[1] + ssum[2] + ssum[3];
  float inv = 1.f / s;
  float* dst = probs + (size_t)b * 1024 * VOC + v;
#pragma unroll
  for (int i = 0; i < 4; ++i) {
    int t = threadIdx.x + 256 * i;
    dst[(size_t)t * VOC] = vals[i] * inv;
  }
}

// ------------------------- per-row -log_softmax_V(probs)[target] partials
__global__ __launch_bounds__(256) void loss_rows_kernel(
    const float* __restrict__ probs, const int* __restrict__ tgt,
    float* __restrict__ partial) {
  int wv = threadIdx.x >> 6, lane = threadIdx.x & 63;
  int row = blockIdx.x * 4 + wv;
  const float* p = probs + (size_t)row * VOC;
  float x0 = p[lane];
  float x1 = (lane == 0) ? p[64] : -1e30f;
  float m = fmaxf(x0, x1);
#pragma unroll
  for (int off = 32; off; off >>= 1) m = fmaxf(m, __shfl_xor(m, off));
  float s = __expf(x0 - m) + ((lane == 0) ? __expf(x1 - m) : 0.f);
#pragma unroll
  for (int off = 32; off; off >>= 1) s += __shfl_xor(s, off);
  if (lane == 0) {
    int tg = tgt[row];
    partial[row] = (p[tg] - m) - logf(s);
  }
}

__global__ __launch_bounds__(256) void loss_final_kernel(
    const float* __restrict__ partial, float* __restrict__ out) {
  float s = 0.f;
  for (int i = threadIdx.x; i < Mrow; i += 256) s += partial[i];
#pragma unroll
  for (int off = 32; off; off >>= 1) s += __shfl_xor(s, off);
  __shared__ float sw[4];
  int wv = threadIdx.x >> 6, ln = threadIdx.x & 63;
  if (ln == 0) sw[wv] = s;
  __syncthreads();
  if (threadIdx.x == 0) out[0] = -(sw[0] + sw[1] + sw[2] + sw[3]) / (float)Mrow;
}

// ------------------------------------------------------------------ launch
extern "C" void kernel_launch(void* const* d_in, const int* in_sizes, int n_in,
                              void* d_out, int out_size, void* d_ws,
                              size_t ws_size, hipStream_t stream) {
  (void)in_sizes; (void)n_in; (void)out_size; (void)ws_size;
  const int*   tok    = (const int*)d_in[0];
  const int*   target = (const int*)d_in[1];
  const float* Wtok   = (const float*)d_in[3];
  const float* Wpos   = (const float*)d_in[4];
  const float* Wq = (const float*)d_in[5];  const float* bq = (const float*)d_in[6];
  const float* Wk = (const float*)d_in[7];  const float* bk = (const float*)d_in[8];
  const float* Wv = (const float*)d_in[9];  const float* bv = (const float*)d_in[10];
  const float* W1 = (const float*)d_in[11]; const float* b1 = (const float*)d_in[12];
  const float* W2 = (const float*)d_in[13]; const float* b2 = (const float*)d_in[14];
  const float* lnw = (const float*)d_in[15];
  const float* Wf = (const float*)d_in[16]; const float* bf = (const float*)d_in[17];
  float* out = (float*)d_out;

  char* p = (char*)d_ws;
  unsigned short* Xb    = (unsigned short*)p; p += (size_t)Mrow * 1024 * 2;
  unsigned short* QKVb  = (unsigned short*)p; p += (size_t)Mrow * 3072 * 2;
  unsigned short* Vt    = (unsigned short*)p; p += (size_t)64 * 64 * 1024 * 2;
  unsigned short* Hb    = (unsigned short*)p; p += (size_t)Mrow * 1024 * 2;
  unsigned short* F2b   = (unsigned short*)p; p += (size_t)Mrow * 1024 * 2;
  unsigned short* FF1b  = (unsigned short*)p; p += (size_t)Mrow * 4096 * 2;
  unsigned short* WqkvT = (unsigned short*)p; p += (size_t)3072 * 1024 * 2;
  unsigned short* W1T   = (unsigned short*)p; p += (size_t)4096 * 1024 * 2;
  unsigned short* W2T   = (unsigned short*)p; p += (size_t)1024 * 4096 * 2;
  unsigned short* WfT   = (unsigned short*)p; p += (size_t)128 * 1024 * 2;
  float* bqkv = (float*)p; p += 3072 * 4;
  float* bfp  = (float*)p; p += 128 * 4;
  float* LOG  = (float*)p; p += (size_t)Mrow * 128 * 4;
  float* PART = (float*)p; p += Mrow * 4;

  wt_conv<<<dim3(32, 32), 256, 0, stream>>>(Wq, WqkvT,                1024, 1024);
  wt_conv<<<dim3(32, 32), 256, 0, stream>>>(Wk, WqkvT + 1024 * 1024,  1024, 1024);
  wt_conv<<<dim3(32, 32), 256, 0, stream>>>(Wv, WqkvT + 2048 * 1024,  1024, 1024);
  wt_conv<<<dim3(32, 128), 256, 0, stream>>>(W1, W1T, 1024, 4096);
  wt_conv<<<dim3(128, 32), 256, 0, stream>>>(W2, W2T, 4096, 1024);
  wt_conv<<<dim3(32, 4), 256, 0, stream>>>(Wf, WfT, 1024, VOC);
  bias_prep<<<13, 256, 0, stream>>>(bq, bk, bv, bf, bqkv, bfp);

  embed_bf<<<Mrow, 256, 0, stream>>>(tok, Wtok, Wpos, Xb);

  for (int l = 0; l < NL; ++l) {
    // QKV: 64x128 tile (48KB LDS -> 3 blk/CU, 1536 blocks), V written to Vt
    gemm_mfma<64, 128, false, false, true><<<dim3(64, 24), 256, 0, stream>>>(
        Xb, WqkvT, bqkv, QKVb, Vt, 3072, 1024);
    attn_mfma<<<dim3(16, 64), 256, 0, stream>>>(QKVb, Vt, Hb);
    ln_res_bf<<<Mrow, 256, 0, stream>>>(Hb, lnw, F2b);            // h + ln(h)
    gemm_mfma<128, 128, true, false, false><<<dim3(32, 32), 256, 0, stream>>>(
        F2b, W1T, b1, FF1b, nullptr, 4096, 1024);                 // relu(hW1+b1)
    gemm_mfma<64, 128, false, false, false><<<dim3(64, 8), 256, 0, stream>>>(
        FF1b, W2T, b2, Hb, nullptr, 1024, 4096);                  // ff2
    ln_res_bf<<<Mrow, 256, 0, stream>>>(Hb, lnw, Xb);             // ff + ln(ff)
  }

  gemm_mfma<64, 128, false, true, false><<<dim3(64, 1), 256, 0, stream>>>(
      Xb, WfT, bfp, LOG, nullptr, 128, 1024);                     // logits (f32)
  softmaxT_kernel<<<4 * VOC, 256, 0, stream>>>(LOG, out + 1);
  loss_rows_kernel<<<Mrow / 4, 256, 0, stream>>>(out + 1, target, PART);
  loss_final_kernel<<<1, 256, 0, stream>>>(PART, out);
}